// Round 11
// baseline (966.032 us; speedup 1.0000x reference)
//
#include <hip/hip_runtime.h>
#include <stdint.h>

typedef _Float16 f16;
typedef __attribute__((ext_vector_type(8))) _Float16 f16x8;
typedef __attribute__((ext_vector_type(4))) _Float16 f16x4;
typedef __attribute__((ext_vector_type(4))) float f32x4;
typedef __attribute__((ext_vector_type(16))) float f32x16;

// async global->LDS, 16B per lane. LDS dest is wave-uniform base (+lane*16 in HW).
__device__ __forceinline__ void gload16(void* lds, const void* gc) {
  void* g = const_cast<void*>(gc);
  __builtin_amdgcn_global_load_lds((__attribute__((address_space(1))) void*)g,
                                   (__attribute__((address_space(3))) void*)lds,
                                   16, 0, 0);
}

// ---------------- f32 -> f16 cast (plain) ----------------
__global__ __launch_bounds__(256) void k_cast(const float* __restrict__ in,
                                              f16* __restrict__ out, int n4) {
  int stride = gridDim.x * blockDim.x;
  for (int i = blockIdx.x * blockDim.x + threadIdx.x; i < n4; i += stride) {
    float4 v = ((const float4*)in)[i];
    f16x4 o;
    o[0] = (f16)v.x; o[1] = (f16)v.y; o[2] = (f16)v.z; o[3] = (f16)v.w;
    ((f16x4*)out)[i] = o;
  }
}

// 4 independent cast jobs selected by blockIdx.y (equal sizes)
__global__ __launch_bounds__(256) void k_cast4(const float* __restrict__ s0, const float* __restrict__ s1,
                                               const float* __restrict__ s2, const float* __restrict__ s3,
                                               f16* __restrict__ d0, f16* __restrict__ d1,
                                               f16* __restrict__ d2, f16* __restrict__ d3, int n4) {
  const int which = blockIdx.y;
  const float* in = which == 0 ? s0 : which == 1 ? s1 : which == 2 ? s2 : s3;
  f16* out = which == 0 ? d0 : which == 1 ? d1 : which == 2 ? d2 : d3;
  int stride = gridDim.x * blockDim.x;
  for (int i = blockIdx.x * blockDim.x + threadIdx.x; i < n4; i += stride) {
    float4 v = ((const float4*)in)[i];
    f16x4 o;
    o[0] = (f16)v.x; o[1] = (f16)v.y; o[2] = (f16)v.z; o[3] = (f16)v.w;
    ((f16x4*)out)[i] = o;
  }
}

// 2 independent cast jobs selected by blockIdx.y
__global__ __launch_bounds__(256) void k_cast2w(const float* __restrict__ s0, const float* __restrict__ s1,
                                                f16* __restrict__ d0, f16* __restrict__ d1, int n4) {
  const int which = blockIdx.y;
  const float* in = which == 0 ? s0 : s1;
  f16* out = which == 0 ? d0 : d1;
  int stride = gridDim.x * blockDim.x;
  for (int i = blockIdx.x * blockDim.x + threadIdx.x; i < n4; i += stride) {
    float4 v = ((const float4*)in)[i];
    f16x4 o;
    o[0] = (f16)v.x; o[1] = (f16)v.y; o[2] = (f16)v.z; o[3] = (f16)v.w;
    ((f16x4*)out)[i] = o;
  }
}

// ---------------- V transpose: [BH][L][128] -> [BH][128][L] ----------------
__global__ __launch_bounds__(256) void k_transpose_v(const f16* __restrict__ vp,
                                                     f16* __restrict__ vt) {
  __shared__ __attribute__((aligned(16))) f16 tile[64][66];
  const int lt = blockIdx.x, dt = blockIdx.y, bh = blockIdx.z;
  const int t = threadIdx.x;
  const int r = t >> 3, c = 8 * (t & 7);
  const f16* src = vp + ((size_t)bh * 2048 + lt * 64) * 128 + dt * 64;
#pragma unroll
  for (int i = 0; i < 2; ++i) {
    union { f16x8 v; unsigned u[4]; } uu;
    uu.v = *(const f16x8*)&src[(size_t)(i * 32 + r) * 128 + c];
#pragma unroll
    for (int j = 0; j < 4; ++j)
      *(unsigned*)&tile[i * 32 + r][c + 2 * j] = uu.u[j];
  }
  __syncthreads();
  f16* dst = vt + ((size_t)bh * 128 + dt * 64) * 2048 + lt * 64;
#pragma unroll
  for (int i = 0; i < 2; ++i) {
    const int dr = i * 32 + r;
    f16x8 o;
#pragma unroll
    for (int e = 0; e < 8; ++e) o[e] = tile[c + e][dr];
    *(f16x8*)&dst[(size_t)dr * 2048 + c] = o;
  }
}

// ---------------- final fuse: out = f32(x1b) + p0 + p1 ----------------
__global__ __launch_bounds__(256) void k_fuseout(const f16* __restrict__ x1b,
                                                 const float* __restrict__ p0,
                                                 const float* __restrict__ p1,
                                                 float* __restrict__ out, int n4) {
  int stride = gridDim.x * blockDim.x;
  for (int i = blockIdx.x * blockDim.x + threadIdx.x; i < n4; i += stride) {
    float4 a = ((const float4*)p0)[i];
    float4 b = ((const float4*)p1)[i];
    f16x4 xb = ((const f16x4*)x1b)[i];
    float4 o;
    o.x = (float)xb[0] + a.x + b.x;
    o.y = (float)xb[1] + a.y + b.y;
    o.z = (float)xb[2] + a.z + b.z;
    o.w = (float)xb[3] + a.w + b.w;
    ((float4*)out)[i] = o;
  }
}

// ---------------- NT GEMM: C[M,N] = A[M,K] @ B[N,K]^T, fused epilogues ----------------
// EPI 0: QKV -> which=gcol>>11: 0,1 -> outb/outb_lo (hi+lo split storage) at
//        which*8M in [B,H,L,DH] layout; 2 -> outv (plain f16) same layout.
// EPI 1: Wo   -> outb = f16(res[idx] + C)
// EPI 2: Up   -> outb = f16(relu(C + bias[col]))
// EPI 3: Down partial -> (z ? outf2 : outf)[idx] = C   (f32, no residual)
template <int EPI, int SPLITOUT, int BK>
__global__ __launch_bounds__(256, 4) void gemm_nt(const f16* __restrict__ A,
                                                  const f16* __restrict__ B,
                                                  int Kit, int ld, int N,
                                                  const float* __restrict__ res,
                                                  const float* __restrict__ bias,
                                                  float* __restrict__ outf,
                                                  float* __restrict__ outf2,
                                                  f16* __restrict__ outb,
                                                  f16* __restrict__ outb_lo,
                                                  f16* __restrict__ outv) {
  constexpr int TSZ = 128 * BK;
  constexpr int CH  = 2048;
  constexpr int RPC = CH / BK;
  constexpr int NCH = 128 / RPC;
  constexpr int CW  = BK / 8;
  __shared__ __attribute__((aligned(16))) f16 As[TSZ];
  __shared__ __attribute__((aligned(16))) f16 Bs[TSZ];
  const int t = threadIdx.x;
  const int l = t & 63;
  const int w = t >> 6;
  const int wr = w >> 1, wc = w & 1;

  // XCD-aware bijective swizzle (nwg % 8 == 0 for all our grids)
  const int nwg = gridDim.x * gridDim.y;
  const int id = blockIdx.y * gridDim.x + blockIdx.x;
  const int sw = (id & 7) * (nwg >> 3) + (id >> 3);
  const int bn = sw % gridDim.x;
  const int bm = sw / gridDim.x;
  const int k0 = blockIdx.z * Kit;

  f32x4 acc[4][4] = {};

  const size_t aoff = (size_t)bm * 128 * ld + k0;
  const size_t boff = (size_t)bn * 128 * ld + k0;

  const int sr = t / CW;
  const int sc = 8 * (t % CW);
  const int lbase = w * 512;

  const int lr = l & 15, lq = l >> 4;
  const int nk = Kit / BK;
  for (int kt = 0; kt < nk; ++kt) {
    const size_t gbase = (size_t)kt * BK + (size_t)sr * ld + sc;
#pragma unroll
    for (int j = 0; j < NCH; ++j) {
      gload16(As + j * CH + lbase, A + aoff + (size_t)j * RPC * ld + gbase);
      gload16(Bs + j * CH + lbase, B + boff + (size_t)j * RPC * ld + gbase);
    }
    __syncthreads();
#pragma unroll
    for (int kk = 0; kk < BK / 32; ++kk) {
      f16x8 af[4], bfr[4];
#pragma unroll
      for (int m = 0; m < 4; ++m)
        af[m] = *(const f16x8*)&As[(wr * 64 + m * 16 + lr) * BK + kk * 32 + 8 * lq];
#pragma unroll
      for (int n = 0; n < 4; ++n)
        bfr[n] = *(const f16x8*)&Bs[(wc * 64 + n * 16 + lr) * BK + kk * 32 + 8 * lq];
#pragma unroll
      for (int m = 0; m < 4; ++m)
#pragma unroll
        for (int n = 0; n < 4; ++n)
          acc[m][n] = __builtin_amdgcn_mfma_f32_16x16x32_f16(af[m], bfr[n], acc[m][n], 0, 0, 0);
    }
    __syncthreads();
  }

  const size_t QKS = (size_t)8 << 20;
#pragma unroll
  for (int m = 0; m < 4; ++m) {
#pragma unroll
    for (int r = 0; r < 4; ++r) {
      const int grow = bm * 128 + wr * 64 + m * 16 + lq * 4 + r;
#pragma unroll
      for (int n = 0; n < 4; ++n) {
        const int gcol = bn * 128 + wc * 64 + n * 16 + lr;
        const float v = acc[m][n][r];
        if constexpr (EPI == 0) {
          const int which = gcol >> 11;
          const int hcol = gcol & 2047;
          const int bb = grow >> 11, ll = grow & 2047;
          const int hh = hcol >> 7, dh = hcol & 127;
          const size_t idx = ((size_t)((bb * 16 + hh) * 2048 + ll) << 7) + dh;
          const f16 hv = (f16)v;
          if (which == 2) {
            outv[idx] = hv;
          } else {
            outb[which * QKS + idx] = hv;
            if constexpr (SPLITOUT) outb_lo[which * QKS + idx] = (f16)(v - (float)hv);
          }
        } else if constexpr (EPI == 1) {
          const size_t idx = (size_t)grow * N + gcol;
          outb[idx] = (f16)(res[idx] + v);
        } else if constexpr (EPI == 2) {
          const size_t idx = (size_t)grow * N + gcol;
          outb[idx] = (f16)fmaxf(v + bias[gcol], 0.f);
        } else {
          const size_t idx = (size_t)grow * N + gcol;
          (blockIdx.z ? outf2 : outf)[idx] = v;
        }
      }
    }
  }
}

// ---------------- causal flash attention, 32x32 MFMA ----------------
// Block = 128 q-rows (4 waves x 32 rows each), grid (16, BH), heavy-first.
// Split-precision QK^T (3-pass), defer-max, granule-XOR-swizzled LDS
// (g' = g ^ (row&7)) so b128 reads hit the 4-way floor instead of 16/32-way.
// 32x32x16 C/D: col = lane&31, row = (reg&3) + 8*(reg>>2) + 4*(lane>>5).
__global__ __launch_bounds__(256) void k_attn(const f16* __restrict__ q_hi,
                                              const f16* __restrict__ q_lo,
                                              const f16* __restrict__ k_hi,
                                              const f16* __restrict__ k_lo,
                                              const f16* __restrict__ vtp,
                                              f16* __restrict__ op) {
  __shared__ __attribute__((aligned(16))) f16 Ks_hi[64 * 128];
  __shared__ __attribute__((aligned(16))) f16 Ks_lo[64 * 128];
  __shared__ __attribute__((aligned(16))) f16 Vs[128 * 64];
  __shared__ __attribute__((aligned(16))) f16 Ps[4][32 * 64];
  const int t = threadIdx.x, l = t & 63, w = t >> 6;
  const int qb = 15 - (int)blockIdx.x;  // heavy blocks first
  const int bh = blockIdx.y;
  const int q0 = qb * 128;
  const int lh = l >> 5, lm = l & 31;
  const int wrow0 = q0 + 32 * w;        // wave's first q-row
  const int myrow = wrow0 + lm;         // lane's A-operand row

  const f16* qhp = q_hi + (size_t)bh * 2048 * 128;
  const f16* qlp = q_lo + (size_t)bh * 2048 * 128;
  const f16* khp = k_hi + (size_t)bh * 2048 * 128;
  const f16* klp = k_lo + (size_t)bh * 2048 * 128;
  const f16* vhp = vtp + (size_t)bh * 128 * 2048;

  const int krow = t >> 4, kg = t & 15;  // K staging: 16 rows/pass, 16 granules/row
  const int vrow = t >> 3, vg = t & 7;   // V staging: 32 rows/pass, 8 granules/row

  // Q fragments in registers: rows = myrow, k-chunks of 16 (8 per lane-half)
  f16x8 aqh[8], aql[8];
#pragma unroll
  for (int c = 0; c < 8; ++c) {
    const size_t qi = (size_t)myrow * 128 + c * 16 + 8 * lh;
    aqh[c] = *(const f16x8*)&qhp[qi];
    aql[c] = *(const f16x8*)&qlp[qi];
  }

  f32x16 acc[4] = {};  // col-tile ct: dcols ct*32+lm; element j <-> row map below
  float mr[16], sr[16];
#pragma unroll
  for (int j = 0; j < 16; ++j) { mr[j] = -1e30f; sr[j] = 0.f; }

  const int ntile = 2 * qb + 2;
  for (int kt = 0; kt < ntile; ++kt) {
    // transient staging regs (die at ds_write; round-9 lesson: no cross-loop liveness)
    f16x8 tkh[4], tkl[4], tv[4];
#pragma unroll
    for (int i = 0; i < 4; ++i) {
      const size_t ki = (size_t)(kt * 64 + i * 16 + krow) * 128 + 8 * kg;
      tkh[i] = *(const f16x8*)&khp[ki];
      tkl[i] = *(const f16x8*)&klp[ki];
      tv[i] = *(const f16x8*)&vhp[(size_t)(i * 32 + vrow) * 2048 + kt * 64 + 8 * vg];
    }
    __syncthreads();  // prior tile's LDS reads done
#pragma unroll
    for (int i = 0; i < 4; ++i) {
      const int kr = i * 16 + krow;
      const int g = kg ^ (kr & 7);
      *(f16x8*)&Ks_hi[kr * 128 + 8 * g] = tkh[i];
      *(f16x8*)&Ks_lo[kr * 128 + 8 * g] = tkl[i];
      const int vr = i * 32 + vrow;
      const int gv = vg ^ (vr & 7);
      *(f16x8*)&Vs[vr * 64 + 8 * gv] = tv[i];
    }
    __syncthreads();

    if (kt * 64 >= wrow0 + 32) continue;  // wave fully masked (trailing tiles only)

    // --- QK^T: 2 key-subtiles x 8 d-chunks x 3-pass split ---
    f32x16 s0, s1;
    __builtin_amdgcn_s_setprio(1);
    {
      f32x16 zh = {}, zl = {};
#pragma unroll
      for (int c = 0; c < 8; ++c) {
        const int g = (2 * c + lh) ^ (lm & 7);
        const f16x8 bh_ = *(const f16x8*)&Ks_hi[lm * 128 + 8 * g];
        const f16x8 bl_ = *(const f16x8*)&Ks_lo[lm * 128 + 8 * g];
        zh = __builtin_amdgcn_mfma_f32_32x32x16_f16(aqh[c], bh_, zh, 0, 0, 0);
        zl = __builtin_amdgcn_mfma_f32_32x32x16_f16(aql[c], bh_, zl, 0, 0, 0);
        zl = __builtin_amdgcn_mfma_f32_32x32x16_f16(aqh[c], bl_, zl, 0, 0, 0);
      }
      s0 = zh + zl;
    }
    {
      f32x16 zh = {}, zl = {};
#pragma unroll
      for (int c = 0; c < 8; ++c) {
        const int g = (2 * c + lh) ^ (lm & 7);  // (32+lm)&7 == lm&7
        const f16x8 bh_ = *(const f16x8*)&Ks_hi[(32 + lm) * 128 + 8 * g];
        const f16x8 bl_ = *(const f16x8*)&Ks_lo[(32 + lm) * 128 + 8 * g];
        zh = __builtin_amdgcn_mfma_f32_32x32x16_f16(aqh[c], bh_, zh, 0, 0, 0);
        zl = __builtin_amdgcn_mfma_f32_32x32x16_f16(aql[c], bh_, zl, 0, 0, 0);
        zl = __builtin_amdgcn_mfma_f32_32x32x16_f16(aqh[c], bl_, zl, 0, 0, 0);
      }
      s1 = zh + zl;
    }
    __builtin_amdgcn_s_setprio(0);

    // causal mask (only tiles that touch the diagonal for this wave)
    if (kt * 64 + 63 > wrow0) {
#pragma unroll
      for (int j = 0; j < 16; ++j) {
        const int rg = wrow0 + (j & 3) + 8 * (j >> 2) + 4 * lh;
        if (kt * 64 + lm > rg) s0[j] = -1e30f;
        if (kt * 64 + 32 + lm > rg) s1[j] = -1e30f;
      }
    }

    // --- softmax: per-row max over 32 lanes (keys), defer-max rescale ---
    float mx[16];
#pragma unroll
    for (int j = 0; j < 16; ++j) {
      float m = fmaxf(s0[j], s1[j]);
#pragma unroll
      for (int off = 1; off < 32; off <<= 1)
        m = fmaxf(m, __shfl_xor(m, off));
      mx[j] = m;
    }
    bool grew = false;
#pragma unroll
    for (int j = 0; j < 16; ++j) grew = grew || (mx[j] > mr[j] + 8.f);
    if (__any(grew)) {
#pragma unroll
      for (int j = 0; j < 16; ++j) {
        const float mnew = fmaxf(mr[j], mx[j]);
        const float sc = __expf(mr[j] - mnew);
        mr[j] = mnew;
        sr[j] *= sc;
#pragma unroll
        for (int ct = 0; ct < 4; ++ct) acc[ct][j] *= sc;
      }
    }
#pragma unroll
    for (int j = 0; j < 16; ++j) {
      const int rjl = (j & 3) + 8 * (j >> 2) + 4 * lh;  // row local 0..31
      const float p0v = __expf(s0[j] - mr[j]);          // bounded by e^8 when deferred
      const float p1v = __expf(s1[j] - mr[j]);
      float ts = p0v + p1v;
#pragma unroll
      for (int off = 1; off < 32; off <<= 1)
        ts += __shfl_xor(ts, off);
      sr[j] += ts;
      const int g0 = (lm >> 3) ^ (rjl & 7);
      Ps[w][rjl * 64 + 8 * g0 + (lm & 7)] = (f16)p0v;
      const int g1 = (4 + (lm >> 3)) ^ (rjl & 7);
      Ps[w][rjl * 64 + 8 * g1 + (lm & 7)] = (f16)p1v;
    }

    // --- PV: P A-frags (row = lm, k-chunks of 16 keys), V B-frags (col = dcol) ---
    f16x8 pf[4];
#pragma unroll
    for (int kk = 0; kk < 4; ++kk) {
      const int g = (2 * kk + lh) ^ (lm & 7);
      pf[kk] = *(const f16x8*)&Ps[w][lm * 64 + 8 * g];
    }
    __builtin_amdgcn_s_setprio(1);
#pragma unroll
    for (int ct = 0; ct < 4; ++ct) {
      const int dcol = ct * 32 + lm;
#pragma unroll
      for (int kk = 0; kk < 4; ++kk) {
        const int gv = (2 * kk + lh) ^ (dcol & 7);
        const f16x8 bv = *(const f16x8*)&Vs[dcol * 64 + 8 * gv];
        acc[ct] = __builtin_amdgcn_mfma_f32_32x32x16_f16(pf[kk], bv, acc[ct], 0, 0, 0);
      }
    }
    __builtin_amdgcn_s_setprio(0);
  }

  const int bb = bh >> 4, hh = bh & 15;
#pragma unroll
  for (int j = 0; j < 16; ++j) {
    const int rg = wrow0 + (j & 3) + 8 * (j >> 2) + 4 * lh;
    const float inv = 1.f / sr[j];
    const size_t row = (size_t)(bb * 2048 + rg);
#pragma unroll
    for (int ct = 0; ct < 4; ++ct)
      op[row * 2048 + hh * 128 + ct * 32 + lm] = (f16)(acc[ct][j] * inv);
  }
}

extern "C" void kernel_launch(void* const* d_in, const int* in_sizes, int n_in,
                              void* d_out, int out_size, void* d_ws, size_t ws_size,
                              hipStream_t stream) {
  const float* x   = (const float*)d_in[0];
  const float* Wq  = (const float*)d_in[2];
  const float* Wk  = (const float*)d_in[3];
  const float* Wv  = (const float*)d_in[4];
  const float* Wo  = (const float*)d_in[5];
  const float* Wup = (const float*)d_in[6];
  const float* bup = (const float*)d_in[7];
  const float* Wdn = (const float*)d_in[8];
  float* out = (float*)d_out;

  const size_t M1 = 1u << 20;
  f16* W = (f16*)d_ws;
  // workspace layout (units of M1 f16 elems); overlays reuse dead regions:
  //  [0..8)    x_hi (dead after QKV gemm)     -> x1b overlay (live to fuseout)
  //  [8..20)   wqkv_hi (dead after QKV)
  //  [20..24)  wo_hi (dead after Wo)
  //  [24..40)  wup_hi (dead after Up)         -> p0 overlay (8M floats)
  //  [40..56)  wdn_hi (live to Down)
  //  [56..88)  q_hi/k_hi/q_lo/k_lo (dead after attn) -> hb overlay [56..88)
  //  [88..96)  vp (V proj; attn out; dead after Wo)  -> p1 overlay [88..104)
  //  [96..104) vtb (dead after attn)
  f16* x_hi    = W + 0 * M1;
  f16* wqkv_hi = W + 8 * M1;
  f16* wo_hi   = W + 20 * M1;
  f16* wup_hi  = W + 24 * M1;
  f16* wdn_hi  = W + 40 * M1;
  f16* q_hi    = W + 56 * M1;
  f16* q_lo    = W + 72 * M1;
  f16* vp      = W + 88 * M1;
  f16* vtb     = W + 96 * M1;
  // overlays (checked against live sets per stage):
  f16* x1b   = x_hi;                  // [0..8)  written by Wo, read by Up+fuseout
  float* p0  = (float*)(W + 24 * M1); // [24..40) — wup dead at Down
  f16* hb    = W + 56 * M1;           // [56..88) — q/k hi/lo dead after attn
  float* p1  = (float*)(W + 88 * M1); // [88..104) — vp/vtb dead after Wo
  f16* attno = vp;
  if (ws_size < (size_t)104 * M1 * sizeof(f16)) return;  // 208 MB

  auto cg = [](size_t n4) { size_t g = (n4 + 255) / 256; return (unsigned)(g > 2048 ? 2048 : g); };
  dim3 b256(256);
  k_cast<<<cg(2 * M1), b256, 0, stream>>>(x, x_hi, (int)(2 * M1));
  k_cast4<<<dim3(cg(1 * M1), 4), b256, 0, stream>>>(
      Wq, Wk, Wv, Wo,
      wqkv_hi, wqkv_hi + 4 * M1, wqkv_hi + 8 * M1, wo_hi, (int)(1 * M1));
  k_cast2w<<<dim3(cg(4 * M1), 2), b256, 0, stream>>>(
      Wup, Wdn, wup_hi, wdn_hi, (int)(4 * M1));

  // fused Q+K+V projection: single-pass f16, split (hi+lo) OUTPUT for Q,K.
  gemm_nt<0, 1, 64><<<dim3(48, 32), b256, 0, stream>>>(
      x_hi, wqkv_hi, 2048, 2048, 6144,
      nullptr, nullptr, nullptr, nullptr, q_hi, q_lo, vp);
  k_transpose_v<<<dim3(32, 2, 32), b256, 0, stream>>>(vp, vtb);
  k_attn<<<dim3(16, 32), b256, 0, stream>>>(
      q_hi, q_lo, q_hi + 8 * M1, q_lo + 8 * M1, vtb, attno);
  // Wo projection + residual -> x1b (f16)
  gemm_nt<1, 0, 64><<<dim3(16, 32), b256, 0, stream>>>(
      attno, wo_hi, 2048, 2048, 2048,
      x, nullptr, nullptr, nullptr, x1b, nullptr, nullptr);
  // Up + bias + relu -> hb
  gemm_nt<2, 0, 64><<<dim3(64, 32), b256, 0, stream>>>(
      x1b, wup_hi, 2048, 2048, 8192,
      nullptr, bup, nullptr, nullptr, hb, nullptr, nullptr);
  // Down, K split 2x -> f32 partials
  gemm_nt<3, 0, 64><<<dim3(16, 32, 2), b256, 0, stream>>>(
      hb, wdn_hi, 4096, 8192, 2048,
      nullptr, nullptr, p0, p1, nullptr, nullptr, nullptr);
  // out = f32(x1b) + p0 + p1
  k_fuseout<<<2048, b256, 0, stream>>>(x1b, p0, p1, out, (int)(2 * M1));
}

// Round 12
// 854.181 us; speedup vs baseline: 1.1309x; 1.1309x over previous
//
#include <hip/hip_runtime.h>
#include <stdint.h>

typedef _Float16 f16;
typedef __attribute__((ext_vector_type(8))) _Float16 f16x8;
typedef __attribute__((ext_vector_type(4))) _Float16 f16x4;
typedef __attribute__((ext_vector_type(4))) float f32x4;
typedef __attribute__((ext_vector_type(16))) float f32x16;

// async global->LDS, 16B per lane. LDS dest is wave-uniform base (+lane*16 in HW).
__device__ __forceinline__ void gload16(void* lds, const void* gc) {
  void* g = const_cast<void*>(gc);
  __builtin_amdgcn_global_load_lds((__attribute__((address_space(1))) void*)g,
                                   (__attribute__((address_space(3))) void*)lds,
                                   16, 0, 0);
}

// ---------------- f32 -> f16 cast (plain) ----------------
__global__ __launch_bounds__(256) void k_cast(const float* __restrict__ in,
                                              f16* __restrict__ out, int n4) {
  int stride = gridDim.x * blockDim.x;
  for (int i = blockIdx.x * blockDim.x + threadIdx.x; i < n4; i += stride) {
    float4 v = ((const float4*)in)[i];
    f16x4 o;
    o[0] = (f16)v.x; o[1] = (f16)v.y; o[2] = (f16)v.z; o[3] = (f16)v.w;
    ((f16x4*)out)[i] = o;
  }
}

// 4 independent cast jobs selected by blockIdx.y (equal sizes)
__global__ __launch_bounds__(256) void k_cast4(const float* __restrict__ s0, const float* __restrict__ s1,
                                               const float* __restrict__ s2, const float* __restrict__ s3,
                                               f16* __restrict__ d0, f16* __restrict__ d1,
                                               f16* __restrict__ d2, f16* __restrict__ d3, int n4) {
  const int which = blockIdx.y;
  const float* in = which == 0 ? s0 : which == 1 ? s1 : which == 2 ? s2 : s3;
  f16* out = which == 0 ? d0 : which == 1 ? d1 : which == 2 ? d2 : d3;
  int stride = gridDim.x * blockDim.x;
  for (int i = blockIdx.x * blockDim.x + threadIdx.x; i < n4; i += stride) {
    float4 v = ((const float4*)in)[i];
    f16x4 o;
    o[0] = (f16)v.x; o[1] = (f16)v.y; o[2] = (f16)v.z; o[3] = (f16)v.w;
    ((f16x4*)out)[i] = o;
  }
}

// 2 independent cast jobs selected by blockIdx.y
__global__ __launch_bounds__(256) void k_cast2w(const float* __restrict__ s0, const float* __restrict__ s1,
                                                f16* __restrict__ d0, f16* __restrict__ d1, int n4) {
  const int which = blockIdx.y;
  const float* in = which == 0 ? s0 : s1;
  f16* out = which == 0 ? d0 : d1;
  int stride = gridDim.x * blockDim.x;
  for (int i = blockIdx.x * blockDim.x + threadIdx.x; i < n4; i += stride) {
    float4 v = ((const float4*)in)[i];
    f16x4 o;
    o[0] = (f16)v.x; o[1] = (f16)v.y; o[2] = (f16)v.z; o[3] = (f16)v.w;
    ((f16x4*)out)[i] = o;
  }
}

// ---------------- V transpose: [BH][L][128] -> [BH][128][L] ----------------
__global__ __launch_bounds__(256) void k_transpose_v(const f16* __restrict__ vp,
                                                     f16* __restrict__ vt) {
  __shared__ __attribute__((aligned(16))) f16 tile[64][66];
  const int lt = blockIdx.x, dt = blockIdx.y, bh = blockIdx.z;
  const int t = threadIdx.x;
  const int r = t >> 3, c = 8 * (t & 7);
  const f16* src = vp + ((size_t)bh * 2048 + lt * 64) * 128 + dt * 64;
#pragma unroll
  for (int i = 0; i < 2; ++i) {
    union { f16x8 v; unsigned u[4]; } uu;
    uu.v = *(const f16x8*)&src[(size_t)(i * 32 + r) * 128 + c];
#pragma unroll
    for (int j = 0; j < 4; ++j)
      *(unsigned*)&tile[i * 32 + r][c + 2 * j] = uu.u[j];
  }
  __syncthreads();
  f16* dst = vt + ((size_t)bh * 128 + dt * 64) * 2048 + lt * 64;
#pragma unroll
  for (int i = 0; i < 2; ++i) {
    const int dr = i * 32 + r;
    f16x8 o;
#pragma unroll
    for (int e = 0; e < 8; ++e) o[e] = tile[c + e][dr];
    *(f16x8*)&dst[(size_t)dr * 2048 + c] = o;
  }
}

// ---------------- final fuse: out = f32(x1b) + p0 + p1 ----------------
__global__ __launch_bounds__(256) void k_fuseout(const f16* __restrict__ x1b,
                                                 const float* __restrict__ p0,
                                                 const float* __restrict__ p1,
                                                 float* __restrict__ out, int n4) {
  int stride = gridDim.x * blockDim.x;
  for (int i = blockIdx.x * blockDim.x + threadIdx.x; i < n4; i += stride) {
    float4 a = ((const float4*)p0)[i];
    float4 b = ((const float4*)p1)[i];
    f16x4 xb = ((const f16x4*)x1b)[i];
    float4 o;
    o.x = (float)xb[0] + a.x + b.x;
    o.y = (float)xb[1] + a.y + b.y;
    o.z = (float)xb[2] + a.z + b.z;
    o.w = (float)xb[3] + a.w + b.w;
    ((float4*)out)[i] = o;
  }
}

// ---------------- NT GEMM: C[M,N] = A[M,K] @ B[N,K]^T, fused epilogues ----------------
// EPI 0: QKV -> which=gcol>>11: 0,1 -> outb/outb_lo (hi+lo split storage) at
//        which*8M in [B,H,L,DH] layout; 2 -> outv (plain f16) same layout.
// EPI 1: Wo   -> outb = f16(res[idx] + C)
// EPI 2: Up   -> outb = f16(relu(C + bias[col]))
// EPI 3: Down partial -> (z ? outf2 : outf)[idx] = C   (f32, no residual)
template <int EPI, int SPLITOUT, int BK>
__global__ __launch_bounds__(256, 4) void gemm_nt(const f16* __restrict__ A,
                                                  const f16* __restrict__ B,
                                                  int Kit, int ld, int N,
                                                  const float* __restrict__ res,
                                                  const float* __restrict__ bias,
                                                  float* __restrict__ outf,
                                                  float* __restrict__ outf2,
                                                  f16* __restrict__ outb,
                                                  f16* __restrict__ outb_lo,
                                                  f16* __restrict__ outv) {
  constexpr int TSZ = 128 * BK;
  constexpr int CH  = 2048;
  constexpr int RPC = CH / BK;
  constexpr int NCH = 128 / RPC;
  constexpr int CW  = BK / 8;
  __shared__ __attribute__((aligned(16))) f16 As[TSZ];
  __shared__ __attribute__((aligned(16))) f16 Bs[TSZ];
  const int t = threadIdx.x;
  const int l = t & 63;
  const int w = t >> 6;
  const int wr = w >> 1, wc = w & 1;

  // XCD-aware bijective swizzle (nwg % 8 == 0 for all our grids)
  const int nwg = gridDim.x * gridDim.y;
  const int id = blockIdx.y * gridDim.x + blockIdx.x;
  const int sw = (id & 7) * (nwg >> 3) + (id >> 3);
  const int bn = sw % gridDim.x;
  const int bm = sw / gridDim.x;
  const int k0 = blockIdx.z * Kit;

  f32x4 acc[4][4] = {};

  const size_t aoff = (size_t)bm * 128 * ld + k0;
  const size_t boff = (size_t)bn * 128 * ld + k0;

  const int sr = t / CW;
  const int sc = 8 * (t % CW);
  const int lbase = w * 512;

  const int lr = l & 15, lq = l >> 4;
  const int nk = Kit / BK;
  for (int kt = 0; kt < nk; ++kt) {
    const size_t gbase = (size_t)kt * BK + (size_t)sr * ld + sc;
#pragma unroll
    for (int j = 0; j < NCH; ++j) {
      gload16(As + j * CH + lbase, A + aoff + (size_t)j * RPC * ld + gbase);
      gload16(Bs + j * CH + lbase, B + boff + (size_t)j * RPC * ld + gbase);
    }
    __syncthreads();
#pragma unroll
    for (int kk = 0; kk < BK / 32; ++kk) {
      f16x8 af[4], bfr[4];
#pragma unroll
      for (int m = 0; m < 4; ++m)
        af[m] = *(const f16x8*)&As[(wr * 64 + m * 16 + lr) * BK + kk * 32 + 8 * lq];
#pragma unroll
      for (int n = 0; n < 4; ++n)
        bfr[n] = *(const f16x8*)&Bs[(wc * 64 + n * 16 + lr) * BK + kk * 32 + 8 * lq];
#pragma unroll
      for (int m = 0; m < 4; ++m)
#pragma unroll
        for (int n = 0; n < 4; ++n)
          acc[m][n] = __builtin_amdgcn_mfma_f32_16x16x32_f16(af[m], bfr[n], acc[m][n], 0, 0, 0);
    }
    __syncthreads();
  }

  const size_t QKS = (size_t)8 << 20;
#pragma unroll
  for (int m = 0; m < 4; ++m) {
#pragma unroll
    for (int r = 0; r < 4; ++r) {
      const int grow = bm * 128 + wr * 64 + m * 16 + lq * 4 + r;
#pragma unroll
      for (int n = 0; n < 4; ++n) {
        const int gcol = bn * 128 + wc * 64 + n * 16 + lr;
        const float v = acc[m][n][r];
        if constexpr (EPI == 0) {
          const int which = gcol >> 11;
          const int hcol = gcol & 2047;
          const int bb = grow >> 11, ll = grow & 2047;
          const int hh = hcol >> 7, dh = hcol & 127;
          const size_t idx = ((size_t)((bb * 16 + hh) * 2048 + ll) << 7) + dh;
          const f16 hv = (f16)v;
          if (which == 2) {
            outv[idx] = hv;
          } else {
            outb[which * QKS + idx] = hv;
            if constexpr (SPLITOUT) outb_lo[which * QKS + idx] = (f16)(v - (float)hv);
          }
        } else if constexpr (EPI == 1) {
          const size_t idx = (size_t)grow * N + gcol;
          outb[idx] = (f16)(res[idx] + v);
        } else if constexpr (EPI == 2) {
          const size_t idx = (size_t)grow * N + gcol;
          outb[idx] = (f16)fmaxf(v + bias[gcol], 0.f);
        } else {
          const size_t idx = (size_t)grow * N + gcol;
          (blockIdx.z ? outf2 : outf)[idx] = v;
        }
      }
    }
  }
}

// ---------------- causal flash attention, 32x32 MFMA ----------------
// Block = 128 q-rows (4 waves x 32 rows each). Grid = flat 512 blocks with a
// COMPLEMENTARY qb remap: s=flat>>5, bh=flat&31, qb = s<8 ? 15-s : s-8.
// The scheduler co-resides blocks i and i+256 on one CU (observed r11: same-x
// pairing gave 2x-heavy CUs); with this remap each CU's pair does
// (2(15-s)+2)+(2s+2)=34 tile-units -> balanced. Perf-only heuristic.
// Split-precision QK^T (3-pass), defer-max, granule-XOR-swizzled LDS
// (g' = g ^ (row&7)). 32x32x16 C/D: col=lane&31, row=(reg&3)+8*(reg>>2)+4*(lane>>5).
__global__ __launch_bounds__(256) void k_attn(const f16* __restrict__ q_hi,
                                              const f16* __restrict__ q_lo,
                                              const f16* __restrict__ k_hi,
                                              const f16* __restrict__ k_lo,
                                              const f16* __restrict__ vtp,
                                              f16* __restrict__ op) {
  __shared__ __attribute__((aligned(16))) f16 Ks_hi[64 * 128];
  __shared__ __attribute__((aligned(16))) f16 Ks_lo[64 * 128];
  __shared__ __attribute__((aligned(16))) f16 Vs[128 * 64];
  __shared__ __attribute__((aligned(16))) f16 Ps[4][32 * 64];
  const int t = threadIdx.x, l = t & 63, w = t >> 6;
  const int flat = (int)blockIdx.x;        // 0..511
  const int s_ = flat >> 5;                // 0..15
  const int bh = flat & 31;
  const int qb = (s_ < 8) ? (15 - s_) : (s_ - 8);  // complementary pairing
  const int q0 = qb * 128;
  const int lh = l >> 5, lm = l & 31;
  const int wrow0 = q0 + 32 * w;        // wave's first q-row
  const int myrow = wrow0 + lm;         // lane's A-operand row

  const f16* qhp = q_hi + (size_t)bh * 2048 * 128;
  const f16* qlp = q_lo + (size_t)bh * 2048 * 128;
  const f16* khp = k_hi + (size_t)bh * 2048 * 128;
  const f16* klp = k_lo + (size_t)bh * 2048 * 128;
  const f16* vhp = vtp + (size_t)bh * 128 * 2048;

  const int krow = t >> 4, kg = t & 15;  // K staging: 16 rows/pass, 16 granules/row
  const int vrow = t >> 3, vg = t & 7;   // V staging: 32 rows/pass, 8 granules/row

  // Q fragments in registers: rows = myrow, k-chunks of 16 (8 per lane-half)
  f16x8 aqh[8], aql[8];
#pragma unroll
  for (int c = 0; c < 8; ++c) {
    const size_t qi = (size_t)myrow * 128 + c * 16 + 8 * lh;
    aqh[c] = *(const f16x8*)&qhp[qi];
    aql[c] = *(const f16x8*)&qlp[qi];
  }

  f32x16 acc[4] = {};  // col-tile ct: dcols ct*32+lm; element j <-> row map below
  float mr[16], sr[16];
#pragma unroll
  for (int j = 0; j < 16; ++j) { mr[j] = -1e30f; sr[j] = 0.f; }

  const int ntile = 2 * qb + 2;
  for (int kt = 0; kt < ntile; ++kt) {
    // transient staging regs (die at ds_write; round-9 lesson: no cross-loop liveness)
    f16x8 tkh[4], tkl[4], tv[4];
#pragma unroll
    for (int i = 0; i < 4; ++i) {
      const size_t ki = (size_t)(kt * 64 + i * 16 + krow) * 128 + 8 * kg;
      tkh[i] = *(const f16x8*)&khp[ki];
      tkl[i] = *(const f16x8*)&klp[ki];
      tv[i] = *(const f16x8*)&vhp[(size_t)(i * 32 + vrow) * 2048 + kt * 64 + 8 * vg];
    }
    __syncthreads();  // prior tile's LDS reads done
#pragma unroll
    for (int i = 0; i < 4; ++i) {
      const int kr = i * 16 + krow;
      const int g = kg ^ (kr & 7);
      *(f16x8*)&Ks_hi[kr * 128 + 8 * g] = tkh[i];
      *(f16x8*)&Ks_lo[kr * 128 + 8 * g] = tkl[i];
      const int vr = i * 32 + vrow;
      const int gv = vg ^ (vr & 7);
      *(f16x8*)&Vs[vr * 64 + 8 * gv] = tv[i];
    }
    __syncthreads();

    if (kt * 64 >= wrow0 + 32) continue;  // wave fully masked (trailing tiles only)

    // --- QK^T: 2 key-subtiles x 8 d-chunks x 3-pass split ---
    f32x16 s0, s1;
    __builtin_amdgcn_s_setprio(1);
    {
      f32x16 zh = {}, zl = {};
#pragma unroll
      for (int c = 0; c < 8; ++c) {
        const int g = (2 * c + lh) ^ (lm & 7);
        const f16x8 bh_ = *(const f16x8*)&Ks_hi[lm * 128 + 8 * g];
        const f16x8 bl_ = *(const f16x8*)&Ks_lo[lm * 128 + 8 * g];
        zh = __builtin_amdgcn_mfma_f32_32x32x16_f16(aqh[c], bh_, zh, 0, 0, 0);
        zl = __builtin_amdgcn_mfma_f32_32x32x16_f16(aql[c], bh_, zl, 0, 0, 0);
        zl = __builtin_amdgcn_mfma_f32_32x32x16_f16(aqh[c], bl_, zl, 0, 0, 0);
      }
      s0 = zh + zl;
    }
    {
      f32x16 zh = {}, zl = {};
#pragma unroll
      for (int c = 0; c < 8; ++c) {
        const int g = (2 * c + lh) ^ (lm & 7);  // (32+lm)&7 == lm&7
        const f16x8 bh_ = *(const f16x8*)&Ks_hi[(32 + lm) * 128 + 8 * g];
        const f16x8 bl_ = *(const f16x8*)&Ks_lo[(32 + lm) * 128 + 8 * g];
        zh = __builtin_amdgcn_mfma_f32_32x32x16_f16(aqh[c], bh_, zh, 0, 0, 0);
        zl = __builtin_amdgcn_mfma_f32_32x32x16_f16(aql[c], bh_, zl, 0, 0, 0);
        zl = __builtin_amdgcn_mfma_f32_32x32x16_f16(aqh[c], bl_, zl, 0, 0, 0);
      }
      s1 = zh + zl;
    }
    __builtin_amdgcn_s_setprio(0);

    // causal mask (only tiles that touch the diagonal for this wave)
    if (kt * 64 + 63 > wrow0) {
#pragma unroll
      for (int j = 0; j < 16; ++j) {
        const int rg = wrow0 + (j & 3) + 8 * (j >> 2) + 4 * lh;
        if (kt * 64 + lm > rg) s0[j] = -1e30f;
        if (kt * 64 + 32 + lm > rg) s1[j] = -1e30f;
      }
    }

    // --- softmax: per-row max over 32 lanes (keys), defer-max rescale ---
    float mx[16];
#pragma unroll
    for (int j = 0; j < 16; ++j) {
      float m = fmaxf(s0[j], s1[j]);
#pragma unroll
      for (int off = 1; off < 32; off <<= 1)
        m = fmaxf(m, __shfl_xor(m, off));
      mx[j] = m;
    }
    bool grew = false;
#pragma unroll
    for (int j = 0; j < 16; ++j) grew = grew || (mx[j] > mr[j] + 8.f);
    if (__any(grew)) {
#pragma unroll
      for (int j = 0; j < 16; ++j) {
        const float mnew = fmaxf(mr[j], mx[j]);
        const float sc = __expf(mr[j] - mnew);
        mr[j] = mnew;
        sr[j] *= sc;
#pragma unroll
        for (int ct = 0; ct < 4; ++ct) acc[ct][j] *= sc;
      }
    }
#pragma unroll
    for (int j = 0; j < 16; ++j) {
      const int rjl = (j & 3) + 8 * (j >> 2) + 4 * lh;  // row local 0..31
      const float p0v = __expf(s0[j] - mr[j]);          // bounded by e^8 when deferred
      const float p1v = __expf(s1[j] - mr[j]);
      float ts = p0v + p1v;
#pragma unroll
      for (int off = 1; off < 32; off <<= 1)
        ts += __shfl_xor(ts, off);
      sr[j] += ts;
      const int g0 = (lm >> 3) ^ (rjl & 7);
      Ps[w][rjl * 64 + 8 * g0 + (lm & 7)] = (f16)p0v;
      const int g1 = (4 + (lm >> 3)) ^ (rjl & 7);
      Ps[w][rjl * 64 + 8 * g1 + (lm & 7)] = (f16)p1v;
    }

    // --- PV: P A-frags (row = lm, k-chunks of 16 keys), V B-frags (col = dcol) ---
    f16x8 pf[4];
#pragma unroll
    for (int kk = 0; kk < 4; ++kk) {
      const int g = (2 * kk + lh) ^ (lm & 7);
      pf[kk] = *(const f16x8*)&Ps[w][lm * 64 + 8 * g];
    }
    __builtin_amdgcn_s_setprio(1);
#pragma unroll
    for (int ct = 0; ct < 4; ++ct) {
      const int dcol = ct * 32 + lm;
#pragma unroll
      for (int kk = 0; kk < 4; ++kk) {
        const int gv = (2 * kk + lh) ^ (dcol & 7);
        const f16x8 bv = *(const f16x8*)&Vs[dcol * 64 + 8 * gv];
        acc[ct] = __builtin_amdgcn_mfma_f32_32x32x16_f16(pf[kk], bv, acc[ct], 0, 0, 0);
      }
    }
    __builtin_amdgcn_s_setprio(0);
  }

  const int bb = bh >> 4, hh = bh & 15;
#pragma unroll
  for (int j = 0; j < 16; ++j) {
    const int rg = wrow0 + (j & 3) + 8 * (j >> 2) + 4 * lh;
    const float inv = 1.f / sr[j];
    const size_t row = (size_t)(bb * 2048 + rg);
#pragma unroll
    for (int ct = 0; ct < 4; ++ct)
      op[row * 2048 + hh * 128 + ct * 32 + lm] = (f16)(acc[ct][j] * inv);
  }
}

extern "C" void kernel_launch(void* const* d_in, const int* in_sizes, int n_in,
                              void* d_out, int out_size, void* d_ws, size_t ws_size,
                              hipStream_t stream) {
  const float* x   = (const float*)d_in[0];
  const float* Wq  = (const float*)d_in[2];
  const float* Wk  = (const float*)d_in[3];
  const float* Wv  = (const float*)d_in[4];
  const float* Wo  = (const float*)d_in[5];
  const float* Wup = (const float*)d_in[6];
  const float* bup = (const float*)d_in[7];
  const float* Wdn = (const float*)d_in[8];
  float* out = (float*)d_out;

  const size_t M1 = 1u << 20;
  f16* W = (f16*)d_ws;
  // workspace layout (units of M1 f16 elems); overlays reuse dead regions:
  //  [0..8)    x_hi (dead after QKV gemm)     -> x1b overlay (live to fuseout)
  //  [8..20)   wqkv_hi (dead after QKV)
  //  [20..24)  wo_hi (dead after Wo)
  //  [24..40)  wup_hi (dead after Up)         -> p0 overlay (8M floats)
  //  [40..56)  wdn_hi (live to Down)
  //  [56..88)  q_hi/k_hi/q_lo/k_lo (dead after attn) -> hb overlay [56..88)
  //  [88..96)  vp (V proj; attn out; dead after Wo)  -> p1 overlay [88..104)
  //  [96..104) vtb (dead after attn)
  f16* x_hi    = W + 0 * M1;
  f16* wqkv_hi = W + 8 * M1;
  f16* wo_hi   = W + 20 * M1;
  f16* wup_hi  = W + 24 * M1;
  f16* wdn_hi  = W + 40 * M1;
  f16* q_hi    = W + 56 * M1;
  f16* q_lo    = W + 72 * M1;
  f16* vp      = W + 88 * M1;
  f16* vtb     = W + 96 * M1;
  // overlays (checked against live sets per stage):
  f16* x1b   = x_hi;                  // [0..8)  written by Wo, read by Up+fuseout
  float* p0  = (float*)(W + 24 * M1); // [24..40) — wup dead at Down
  f16* hb    = W + 56 * M1;           // [56..88) — q/k hi/lo dead after attn
  float* p1  = (float*)(W + 88 * M1); // [88..104) — vp/vtb dead after Wo
  f16* attno = vp;
  if (ws_size < (size_t)104 * M1 * sizeof(f16)) return;  // 208 MB

  auto cg = [](size_t n4) { size_t g = (n4 + 255) / 256; return (unsigned)(g > 2048 ? 2048 : g); };
  dim3 b256(256);
  k_cast<<<cg(2 * M1), b256, 0, stream>>>(x, x_hi, (int)(2 * M1));
  k_cast4<<<dim3(cg(1 * M1), 4), b256, 0, stream>>>(
      Wq, Wk, Wv, Wo,
      wqkv_hi, wqkv_hi + 4 * M1, wqkv_hi + 8 * M1, wo_hi, (int)(1 * M1));
  k_cast2w<<<dim3(cg(4 * M1), 2), b256, 0, stream>>>(
      Wup, Wdn, wup_hi, wdn_hi, (int)(4 * M1));

  // fused Q+K+V projection: single-pass f16, split (hi+lo) OUTPUT for Q,K.
  gemm_nt<0, 1, 64><<<dim3(48, 32), b256, 0, stream>>>(
      x_hi, wqkv_hi, 2048, 2048, 6144,
      nullptr, nullptr, nullptr, nullptr, q_hi, q_lo, vp);
  k_transpose_v<<<dim3(32, 2, 32), b256, 0, stream>>>(vp, vtb);
  k_attn<<<dim3(512), b256, 0, stream>>>(
      q_hi, q_lo, q_hi + 8 * M1, q_lo + 8 * M1, vtb, attno);
  // Wo projection + residual -> x1b (f16)
  gemm_nt<1, 0, 64><<<dim3(16, 32), b256, 0, stream>>>(
      attno, wo_hi, 2048, 2048, 2048,
      x, nullptr, nullptr, nullptr, x1b, nullptr, nullptr);
  // Up + bias + relu -> hb
  gemm_nt<2, 0, 64><<<dim3(64, 32), b256, 0, stream>>>(
      x1b, wup_hi, 2048, 2048, 8192,
      nullptr, bup, nullptr, nullptr, hb, nullptr, nullptr);
  // Down, K split 2x -> f32 partials
  gemm_nt<3, 0, 64><<<dim3(16, 32, 2), b256, 0, stream>>>(
      hb, wdn_hi, 4096, 8192, 2048,
      nullptr, nullptr, p0, p1, nullptr, nullptr, nullptr);
  // out = f32(x1b) + p0 + p1
  k_fuseout<<<2048, b256, 0, stream>>>(x1b, p0, p1, out, (int)(2 * M1));
}

// Round 14
// 752.690 us; speedup vs baseline: 1.2834x; 1.1348x over previous
//
#include <hip/hip_runtime.h>
#include <stdint.h>

typedef _Float16 f16;
typedef __attribute__((ext_vector_type(8))) _Float16 f16x8;
typedef __attribute__((ext_vector_type(4))) _Float16 f16x4;
typedef __attribute__((ext_vector_type(2))) __fp16 fp16x2;
typedef __attribute__((ext_vector_type(4))) float f32x4;
typedef __attribute__((ext_vector_type(16))) float f32x16;
typedef __attribute__((ext_vector_type(4))) unsigned u32x4;

// async global->LDS, 16B per lane. LDS dest is wave-uniform base (+lane*16 in HW).
__device__ __forceinline__ void gload16(void* lds, const void* gc) {
  void* g = const_cast<void*>(gc);
  __builtin_amdgcn_global_load_lds((__attribute__((address_space(1))) void*)g,
                                   (__attribute__((address_space(3))) void*)lds,
                                   16, 0, 0);
}

__device__ __forceinline__ unsigned pkrtz(float a, float b) {
  union { fp16x2 h; unsigned u; } c;
  c.h = __builtin_amdgcn_cvt_pkrtz(a, b);
  return c.u;
}

// ---------------- f32 -> f16 cast (plain) ----------------
__global__ __launch_bounds__(256) void k_cast(const float* __restrict__ in,
                                              f16* __restrict__ out, int n4) {
  int stride = gridDim.x * blockDim.x;
  for (int i = blockIdx.x * blockDim.x + threadIdx.x; i < n4; i += stride) {
    float4 v = ((const float4*)in)[i];
    f16x4 o;
    o[0] = (f16)v.x; o[1] = (f16)v.y; o[2] = (f16)v.z; o[3] = (f16)v.w;
    ((f16x4*)out)[i] = o;
  }
}

// 4 independent cast jobs selected by blockIdx.y (equal sizes)
__global__ __launch_bounds__(256) void k_cast4(const float* __restrict__ s0, const float* __restrict__ s1,
                                               const float* __restrict__ s2, const float* __restrict__ s3,
                                               f16* __restrict__ d0, f16* __restrict__ d1,
                                               f16* __restrict__ d2, f16* __restrict__ d3, int n4) {
  const int which = blockIdx.y;
  const float* in = which == 0 ? s0 : which == 1 ? s1 : which == 2 ? s2 : s3;
  f16* out = which == 0 ? d0 : which == 1 ? d1 : which == 2 ? d2 : d3;
  int stride = gridDim.x * blockDim.x;
  for (int i = blockIdx.x * blockDim.x + threadIdx.x; i < n4; i += stride) {
    float4 v = ((const float4*)in)[i];
    f16x4 o;
    o[0] = (f16)v.x; o[1] = (f16)v.y; o[2] = (f16)v.z; o[3] = (f16)v.w;
    ((f16x4*)out)[i] = o;
  }
}

// 2 independent cast jobs selected by blockIdx.y
__global__ __launch_bounds__(256) void k_cast2w(const float* __restrict__ s0, const float* __restrict__ s1,
                                                f16* __restrict__ d0, f16* __restrict__ d1, int n4) {
  const int which = blockIdx.y;
  const float* in = which == 0 ? s0 : s1;
  f16* out = which == 0 ? d0 : d1;
  int stride = gridDim.x * blockDim.x;
  for (int i = blockIdx.x * blockDim.x + threadIdx.x; i < n4; i += stride) {
    float4 v = ((const float4*)in)[i];
    f16x4 o;
    o[0] = (f16)v.x; o[1] = (f16)v.y; o[2] = (f16)v.z; o[3] = (f16)v.w;
    ((f16x4*)out)[i] = o;
  }
}

// ---------------- V transpose: [BH][L][128] -> [BH][128][L] ----------------
__global__ __launch_bounds__(256) void k_transpose_v(const f16* __restrict__ vp,
                                                     f16* __restrict__ vt) {
  __shared__ __attribute__((aligned(16))) f16 tile[64][66];
  const int lt = blockIdx.x, dt = blockIdx.y, bh = blockIdx.z;
  const int t = threadIdx.x;
  const int r = t >> 3, c = 8 * (t & 7);
  const f16* src = vp + ((size_t)bh * 2048 + lt * 64) * 128 + dt * 64;
#pragma unroll
  for (int i = 0; i < 2; ++i) {
    union { f16x8 v; unsigned u[4]; } uu;
    uu.v = *(const f16x8*)&src[(size_t)(i * 32 + r) * 128 + c];
#pragma unroll
    for (int j = 0; j < 4; ++j)
      *(unsigned*)&tile[i * 32 + r][c + 2 * j] = uu.u[j];
  }
  __syncthreads();
  f16* dst = vt + ((size_t)bh * 128 + dt * 64) * 2048 + lt * 64;
#pragma unroll
  for (int i = 0; i < 2; ++i) {
    const int dr = i * 32 + r;
    f16x8 o;
#pragma unroll
    for (int e = 0; e < 8; ++e) o[e] = tile[c + e][dr];
    *(f16x8*)&dst[(size_t)dr * 2048 + c] = o;
  }
}

// ---------------- final fuse: out = f32(x1b) + p0 + p1 ----------------
__global__ __launch_bounds__(256) void k_fuseout(const f16* __restrict__ x1b,
                                                 const float* __restrict__ p0,
                                                 const float* __restrict__ p1,
                                                 float* __restrict__ out, int n4) {
  int stride = gridDim.x * blockDim.x;
  for (int i = blockIdx.x * blockDim.x + threadIdx.x; i < n4; i += stride) {
    float4 a = ((const float4*)p0)[i];
    float4 b = ((const float4*)p1)[i];
    f16x4 xb = ((const f16x4*)x1b)[i];
    float4 o;
    o.x = (float)xb[0] + a.x + b.x;
    o.y = (float)xb[1] + a.y + b.y;
    o.z = (float)xb[2] + a.z + b.z;
    o.w = (float)xb[3] + a.w + b.w;
    ((float4*)out)[i] = o;
  }
}

// ---------------- NT GEMM: C[M,N] = A[M,K] @ B[N,K]^T, fused epilogues ----------------
// EPI 0: QKV -> which=gcol>>11: 0,1 -> outb/outb_lo (hi+lo split storage) at
//        which*8M in [B,H,L,DH] layout; 2 -> outv (plain f16) same layout.
// EPI 1: Wo   -> outb = f16(res[idx] + C)
// EPI 2: Up   -> outb = f16(relu(C + bias[col]))
// EPI 3: Down partial -> (z ? outf2 : outf)[idx] = C   (f32, no residual)
template <int EPI, int SPLITOUT, int BK>
__global__ __launch_bounds__(256, 4) void gemm_nt(const f16* __restrict__ A,
                                                  const f16* __restrict__ B,
                                                  int Kit, int ld, int N,
                                                  const float* __restrict__ res,
                                                  const float* __restrict__ bias,
                                                  float* __restrict__ outf,
                                                  float* __restrict__ outf2,
                                                  f16* __restrict__ outb,
                                                  f16* __restrict__ outb_lo,
                                                  f16* __restrict__ outv) {
  constexpr int TSZ = 128 * BK;
  constexpr int CH  = 2048;
  constexpr int RPC = CH / BK;
  constexpr int NCH = 128 / RPC;
  constexpr int CW  = BK / 8;
  __shared__ __attribute__((aligned(16))) f16 As[TSZ];
  __shared__ __attribute__((aligned(16))) f16 Bs[TSZ];
  const int t = threadIdx.x;
  const int l = t & 63;
  const int w = t >> 6;
  const int wr = w >> 1, wc = w & 1;

  // XCD-aware bijective swizzle (nwg % 8 == 0 for all our grids)
  const int nwg = gridDim.x * gridDim.y;
  const int id = blockIdx.y * gridDim.x + blockIdx.x;
  const int sw = (id & 7) * (nwg >> 3) + (id >> 3);
  const int bn = sw % gridDim.x;
  const int bm = sw / gridDim.x;
  const int k0 = blockIdx.z * Kit;

  f32x4 acc[4][4] = {};

  const size_t aoff = (size_t)bm * 128 * ld + k0;
  const size_t boff = (size_t)bn * 128 * ld + k0;

  const int sr = t / CW;
  const int sc = 8 * (t % CW);
  const int lbase = w * 512;

  const int lr = l & 15, lq = l >> 4;
  const int nk = Kit / BK;
  for (int kt = 0; kt < nk; ++kt) {
    const size_t gbase = (size_t)kt * BK + (size_t)sr * ld + sc;
#pragma unroll
    for (int j = 0; j < NCH; ++j) {
      gload16(As + j * CH + lbase, A + aoff + (size_t)j * RPC * ld + gbase);
      gload16(Bs + j * CH + lbase, B + boff + (size_t)j * RPC * ld + gbase);
    }
    __syncthreads();
#pragma unroll
    for (int kk = 0; kk < BK / 32; ++kk) {
      f16x8 af[4], bfr[4];
#pragma unroll
      for (int m = 0; m < 4; ++m)
        af[m] = *(const f16x8*)&As[(wr * 64 + m * 16 + lr) * BK + kk * 32 + 8 * lq];
#pragma unroll
      for (int n = 0; n < 4; ++n)
        bfr[n] = *(const f16x8*)&Bs[(wc * 64 + n * 16 + lr) * BK + kk * 32 + 8 * lq];
#pragma unroll
      for (int m = 0; m < 4; ++m)
#pragma unroll
        for (int n = 0; n < 4; ++n)
          acc[m][n] = __builtin_amdgcn_mfma_f32_16x16x32_f16(af[m], bfr[n], acc[m][n], 0, 0, 0);
    }
    __syncthreads();
  }

  const size_t QKS = (size_t)8 << 20;
#pragma unroll
  for (int m = 0; m < 4; ++m) {
#pragma unroll
    for (int r = 0; r < 4; ++r) {
      const int grow = bm * 128 + wr * 64 + m * 16 + lq * 4 + r;
#pragma unroll
      for (int n = 0; n < 4; ++n) {
        const int gcol = bn * 128 + wc * 64 + n * 16 + lr;
        const float v = acc[m][n][r];
        if constexpr (EPI == 0) {
          const int which = gcol >> 11;
          const int hcol = gcol & 2047;
          const int bb = grow >> 11, ll = grow & 2047;
          const int hh = hcol >> 7, dh = hcol & 127;
          const size_t idx = ((size_t)((bb * 16 + hh) * 2048 + ll) << 7) + dh;
          const f16 hv = (f16)v;
          if (which == 2) {
            outv[idx] = hv;
          } else {
            outb[which * QKS + idx] = hv;
            if constexpr (SPLITOUT) outb_lo[which * QKS + idx] = (f16)(v - (float)hv);
          }
        } else if constexpr (EPI == 1) {
          const size_t idx = (size_t)grow * N + gcol;
          outb[idx] = (f16)(res[idx] + v);
        } else if constexpr (EPI == 2) {
          const size_t idx = (size_t)grow * N + gcol;
          outb[idx] = (f16)fmaxf(v + bias[gcol], 0.f);
        } else {
          const size_t idx = (size_t)grow * N + gcol;
          (blockIdx.z ? outf2 : outf)[idx] = v;
        }
      }
    }
  }
}

// ---------------- causal flash attention, 32x32 MFMA, swapped QK^T ----------------
// Block = 128 q-rows (4 waves x 32). Flat grid 512 + complementary qb remap
// (r12-verified: co-resident pair sums to 34 tile-units).
// QK^T computed SWAPPED: mfma(K_frag, Q_frag) -> C[key][qrow], col=lane&31=qrow,
// so each lane owns ONE q-row with 32 keys in regs (partner lane l^32 holds the
// other 32). Softmax reductions = in-register + 1 shfl_xor(32); P packed via
// v_cvt_pkrtz and exchanged with 8 shfls -> PV A-frags entirely in registers
// (no Ps LDS buffer, no 5-level butterflies on the LDS pipe).
// 32x32x16 C/D: col=lane&31, row=(reg&3)+8*(reg>>2)+4*(lane>>5).
__global__ __launch_bounds__(256) void k_attn(const f16* __restrict__ q_hi,
                                              const f16* __restrict__ q_lo,
                                              const f16* __restrict__ k_hi,
                                              const f16* __restrict__ k_lo,
                                              const f16* __restrict__ vtp,
                                              f16* __restrict__ op) {
  __shared__ __attribute__((aligned(16))) f16 Ks_hi[64 * 128];
  __shared__ __attribute__((aligned(16))) f16 Ks_lo[64 * 128];
  __shared__ __attribute__((aligned(16))) f16 Vs[128 * 64];
  const int t = threadIdx.x, l = t & 63, w = t >> 6;
  const int flat = (int)blockIdx.x;        // 0..511
  const int s_ = flat >> 5;                // 0..15
  const int bh = flat & 31;
  const int qb = (s_ < 8) ? (15 - s_) : (s_ - 8);  // complementary pairing
  const int q0 = qb * 128;
  const int lh = l >> 5, lm = l & 31;
  const int wrow0 = q0 + 32 * w;        // wave's first q-row
  const int myrow = wrow0 + lm;         // lane's q-row (swapped-C col)

  const f16* qhp = q_hi + (size_t)bh * 2048 * 128;
  const f16* qlp = q_lo + (size_t)bh * 2048 * 128;
  const f16* khp = k_hi + (size_t)bh * 2048 * 128;
  const f16* klp = k_lo + (size_t)bh * 2048 * 128;
  const f16* vhp = vtp + (size_t)bh * 128 * 2048;

  const int krow = t >> 4, kg = t & 15;  // K staging: 16 rows/pass, 16 granules/row
  const int vrow = t >> 3, vg = t & 7;   // V staging: 32 rows/pass, 8 granules/row

  // Q fragments (B-operand in swapped QK): col=myrow, k-chunks of 16
  f16x8 aqh[8], aql[8];
#pragma unroll
  for (int c = 0; c < 8; ++c) {
    const size_t qi = (size_t)myrow * 128 + c * 16 + 8 * lh;
    aqh[c] = *(const f16x8*)&qhp[qi];
    aql[c] = *(const f16x8*)&qlp[qi];
  }

  f32x16 acc[4] = {};  // PV out: col=dcol(ct*32+lm), reg j -> qrow (j&3)+8*(j>>2)+4*lh
  float mr = -1e30f, sr = 0.f;  // own row (myrow) running max / sum

  const int ntile = 2 * qb + 2;
  for (int kt = 0; kt < ntile; ++kt) {
    // transient staging regs (die at ds_write)
    f16x8 tkh[4], tkl[4], tv[4];
#pragma unroll
    for (int i = 0; i < 4; ++i) {
      const size_t ki = (size_t)(kt * 64 + i * 16 + krow) * 128 + 8 * kg;
      tkh[i] = *(const f16x8*)&khp[ki];
      tkl[i] = *(const f16x8*)&klp[ki];
      tv[i] = *(const f16x8*)&vhp[(size_t)(i * 32 + vrow) * 2048 + kt * 64 + 8 * vg];
    }
    __syncthreads();  // prior tile's LDS reads done
#pragma unroll
    for (int i = 0; i < 4; ++i) {
      const int kr = i * 16 + krow;
      const int g = kg ^ (kr & 7);
      *(f16x8*)&Ks_hi[kr * 128 + 8 * g] = tkh[i];
      *(f16x8*)&Ks_lo[kr * 128 + 8 * g] = tkl[i];
      const int vr = i * 32 + vrow;
      const int gv = vg ^ (vr & 7);
      *(f16x8*)&Vs[vr * 64 + 8 * gv] = tv[i];
    }
    __syncthreads();

    if (kt * 64 >= wrow0 + 32) continue;  // wave fully masked (trailing tiles only)

    // --- swapped QK^T: S^T[key][qrow], key-subtiles s0 (0..31) and s1 (32..63) ---
    f32x16 s0, s1;
    __builtin_amdgcn_s_setprio(1);
    {
      f32x16 zh = {}, zl = {};
#pragma unroll
      for (int c = 0; c < 8; ++c) {
        const int g = (2 * c + lh) ^ (lm & 7);
        const f16x8 bh_ = *(const f16x8*)&Ks_hi[lm * 128 + 8 * g];
        const f16x8 bl_ = *(const f16x8*)&Ks_lo[lm * 128 + 8 * g];
        zh = __builtin_amdgcn_mfma_f32_32x32x16_f16(bh_, aqh[c], zh, 0, 0, 0);
        zl = __builtin_amdgcn_mfma_f32_32x32x16_f16(bh_, aql[c], zl, 0, 0, 0);
        zl = __builtin_amdgcn_mfma_f32_32x32x16_f16(bl_, aqh[c], zl, 0, 0, 0);
      }
      s0 = zh + zl;
    }
    {
      f32x16 zh = {}, zl = {};
#pragma unroll
      for (int c = 0; c < 8; ++c) {
        const int g = (2 * c + lh) ^ (lm & 7);  // (32+lm)&7 == lm&7
        const f16x8 bh_ = *(const f16x8*)&Ks_hi[(32 + lm) * 128 + 8 * g];
        const f16x8 bl_ = *(const f16x8*)&Ks_lo[(32 + lm) * 128 + 8 * g];
        zh = __builtin_amdgcn_mfma_f32_32x32x16_f16(bh_, aqh[c], zh, 0, 0, 0);
        zl = __builtin_amdgcn_mfma_f32_32x32x16_f16(bh_, aql[c], zl, 0, 0, 0);
        zl = __builtin_amdgcn_mfma_f32_32x32x16_f16(bl_, aqh[c], zl, 0, 0, 0);
      }
      s1 = zh + zl;
    }
    __builtin_amdgcn_s_setprio(0);

    // causal mask: reg j holds key (j&3)+8*(j>>2)+4*lh (s0) / +32 (s1) of row myrow
    if (kt * 64 + 63 > wrow0) {
#pragma unroll
      for (int j = 0; j < 16; ++j) {
        const int keyl = (j & 3) + 8 * (j >> 2) + 4 * lh;
        if (kt * 64 + keyl > myrow) s0[j] = -1e30f;
        if (kt * 64 + 32 + keyl > myrow) s1[j] = -1e30f;
      }
    }

    // --- softmax: in-register row reduce + 1 cross-half exchange ---
    float m = -1e30f;
#pragma unroll
    for (int j = 0; j < 16; ++j) m = fmaxf(m, fmaxf(s0[j], s1[j]));
    m = fmaxf(m, __shfl_xor(m, 32));
    if (__any(m > mr + 8.f)) {  // defer-max rescale (rare)
      const float mnew = fmaxf(mr, m);
      const float sc = __expf(mr - mnew);
      mr = mnew;
      sr *= sc;
#pragma unroll
      for (int j = 0; j < 16; ++j) {
        const float scj = __shfl(sc, (j & 3) + 8 * (j >> 2) + 4 * lh + 32 * (l >> 5 ? 0 : 0));
#pragma unroll
        for (int ct = 0; ct < 4; ++ct) acc[ct][j] *= scj;
      }
    }
    float p0v[16], p1v[16];
    float ts = 0.f;
#pragma unroll
    for (int j = 0; j < 16; ++j) {
      p0v[j] = __expf(s0[j] - mr);  // bounded by e^8 when deferred
      p1v[j] = __expf(s1[j] - mr);
      ts += p0v[j] + p1v[j];
    }
    sr += ts + __shfl_xor(ts, 32);

    // --- pack P to f16 pairs; exchange complementary key-sets across halves ---
    unsigned u[16];
#pragma unroll
    for (int m2 = 0; m2 < 8; ++m2) {
      u[m2] = pkrtz(p0v[2 * m2], p0v[2 * m2 + 1]);
      u[8 + m2] = pkrtz(p1v[2 * m2], p1v[2 * m2 + 1]);
    }
    unsigned ys[8];
#pragma unroll
    for (int m2 = 0; m2 < 8; ++m2) {
      const int q_ = m2 >> 1, h_ = m2 & 1;
      const unsigned xs = lh ? u[4 * q_ + h_] : u[4 * q_ + 2 + h_];  // send what partner needs
      ys[m2] = __shfl_xor(xs, 32);
    }
    // PV A-frags: lane supplies P[row=myrow][keys 16*kk + 8*lh .. +8]
    f16x8 pf[4];
#pragma unroll
    for (int kk = 0; kk < 4; ++kk) {
      union { u32x4 u4; f16x8 h8; } cv;
      if (lh == 0) {
        cv.u4[0] = u[4 * kk];     cv.u4[1] = u[4 * kk + 1];
        cv.u4[2] = ys[2 * kk];    cv.u4[3] = ys[2 * kk + 1];
      } else {
        cv.u4[0] = ys[2 * kk];    cv.u4[1] = ys[2 * kk + 1];
        cv.u4[2] = u[4 * kk + 2]; cv.u4[3] = u[4 * kk + 3];
      }
      pf[kk] = cv.h8;
    }

    // --- PV: O[qrow][dcol] += P x V^T ---
    __builtin_amdgcn_s_setprio(1);
#pragma unroll
    for (int ct = 0; ct < 4; ++ct) {
      const int dcol = ct * 32 + lm;
#pragma unroll
      for (int kk = 0; kk < 4; ++kk) {
        const int gv = (2 * kk + lh) ^ (dcol & 7);
        const f16x8 bv = *(const f16x8*)&Vs[dcol * 64 + 8 * gv];
        acc[ct] = __builtin_amdgcn_mfma_f32_32x32x16_f16(pf[kk], bv, acc[ct], 0, 0, 0);
      }
    }
    __builtin_amdgcn_s_setprio(0);
  }

  const int bb = bh >> 4, hh = bh & 15;
  const float inv = 1.f / sr;  // own row
#pragma unroll
  for (int j = 0; j < 16; ++j) {
    const int rl = (j & 3) + 8 * (j >> 2) + 4 * lh;  // local row of acc reg j
    const float invj = __shfl(inv, rl);
    const size_t row = (size_t)(bb * 2048 + wrow0 + rl);
#pragma unroll
    for (int ct = 0; ct < 4; ++ct)
      op[row * 2048 + hh * 128 + ct * 32 + lm] = (f16)(acc[ct][j] * invj);
  }
}

extern "C" void kernel_launch(void* const* d_in, const int* in_sizes, int n_in,
                              void* d_out, int out_size, void* d_ws, size_t ws_size,
                              hipStream_t stream) {
  const float* x   = (const float*)d_in[0];
  const float* Wq  = (const float*)d_in[2];
  const float* Wk  = (const float*)d_in[3];
  const float* Wv  = (const float*)d_in[4];
  const float* Wo  = (const float*)d_in[5];
  const float* Wup = (const float*)d_in[6];
  const float* bup = (const float*)d_in[7];
  const float* Wdn = (const float*)d_in[8];
  float* out = (float*)d_out;

  const size_t M1 = 1u << 20;
  f16* W = (f16*)d_ws;
  // workspace layout (units of M1 f16 elems); overlays reuse dead regions:
  //  [0..8)    x_hi (dead after QKV gemm)     -> x1b overlay (live to fuseout)
  //  [8..20)   wqkv_hi (dead after QKV)
  //  [20..24)  wo_hi (dead after Wo)
  //  [24..40)  wup_hi (dead after Up)         -> p0 overlay (8M floats)
  //  [40..56)  wdn_hi (live to Down)
  //  [56..88)  q_hi/k_hi/q_lo/k_lo (dead after attn) -> hb overlay [56..88)
  //  [88..96)  vp (V proj; attn out; dead after Wo)  -> p1 overlay [88..104)
  //  [96..104) vtb (dead after attn)
  f16* x_hi    = W + 0 * M1;
  f16* wqkv_hi = W + 8 * M1;
  f16* wo_hi   = W + 20 * M1;
  f16* wup_hi  = W + 24 * M1;
  f16* wdn_hi  = W + 40 * M1;
  f16* q_hi    = W + 56 * M1;
  f16* q_lo    = W + 72 * M1;
  f16* vp      = W + 88 * M1;
  f16* vtb     = W + 96 * M1;
  // overlays (checked against live sets per stage):
  f16* x1b   = x_hi;                  // [0..8)  written by Wo, read by Up+fuseout
  float* p0  = (float*)(W + 24 * M1); // [24..40) — wup dead at Down
  f16* hb    = W + 56 * M1;           // [56..88) — q/k hi/lo dead after attn
  float* p1  = (float*)(W + 88 * M1); // [88..104) — vp/vtb dead after Wo
  f16* attno = vp;
  if (ws_size < (size_t)104 * M1 * sizeof(f16)) return;  // 208 MB

  auto cg = [](size_t n4) { size_t g = (n4 + 255) / 256; return (unsigned)(g > 2048 ? 2048 : g); };
  dim3 b256(256);
  k_cast<<<cg(2 * M1), b256, 0, stream>>>(x, x_hi, (int)(2 * M1));
  k_cast4<<<dim3(cg(1 * M1), 4), b256, 0, stream>>>(
      Wq, Wk, Wv, Wo,
      wqkv_hi, wqkv_hi + 4 * M1, wqkv_hi + 8 * M1, wo_hi, (int)(1 * M1));
  k_cast2w<<<dim3(cg(4 * M1), 2), b256, 0, stream>>>(
      Wup, Wdn, wup_hi, wdn_hi, (int)(4 * M1));

  // fused Q+K+V projection: single-pass f16, split (hi+lo) OUTPUT for Q,K.
  gemm_nt<0, 1, 64><<<dim3(48, 32), b256, 0, stream>>>(
      x_hi, wqkv_hi, 2048, 2048, 6144,
      nullptr, nullptr, nullptr, nullptr, q_hi, q_lo, vp);
  k_transpose_v<<<dim3(32, 2, 32), b256, 0, stream>>>(vp, vtb);
  k_attn<<<dim3(512), b256, 0, stream>>>(
      q_hi, q_lo, q_hi + 8 * M1, q_lo + 8 * M1, vtb, attno);
  // Wo projection + residual -> x1b (f16)
  gemm_nt<1, 0, 64><<<dim3(16, 32), b256, 0, stream>>>(
      attno, wo_hi, 2048, 2048, 2048,
      x, nullptr, nullptr, nullptr, x1b, nullptr, nullptr);
  // Up + bias + relu -> hb
  gemm_nt<2, 0, 64><<<dim3(64, 32), b256, 0, stream>>>(
      x1b, wup_hi, 2048, 2048, 8192,
      nullptr, bup, nullptr, nullptr, hb, nullptr, nullptr);
  // Down, K split 2x -> f32 partials
  gemm_nt<3, 0, 64><<<dim3(16, 32, 2), b256, 0, stream>>>(
      hb, wdn_hi, 4096, 8192, 2048,
      nullptr, nullptr, p0, p1, nullptr, nullptr, nullptr);
  // out = f32(x1b) + p0 + p1
  k_fuseout<<<2048, b256, 0, stream>>>(x1b, p0, p1, out, (int)(2 * M1));
}

// Round 15
// 722.905 us; speedup vs baseline: 1.3363x; 1.0412x over previous
//
#include <hip/hip_runtime.h>
#include <stdint.h>

typedef _Float16 f16;
typedef __attribute__((ext_vector_type(8))) _Float16 f16x8;
typedef __attribute__((ext_vector_type(4))) _Float16 f16x4;
typedef __attribute__((ext_vector_type(2))) __fp16 fp16x2;
typedef __attribute__((ext_vector_type(4))) float f32x4;
typedef __attribute__((ext_vector_type(16))) float f32x16;
typedef __attribute__((ext_vector_type(4))) unsigned u32x4;

// async global->LDS, 16B per lane. LDS dest is wave-uniform base (+lane*16 in HW).
__device__ __forceinline__ void gload16(void* lds, const void* gc) {
  void* g = const_cast<void*>(gc);
  __builtin_amdgcn_global_load_lds((__attribute__((address_space(1))) void*)g,
                                   (__attribute__((address_space(3))) void*)lds,
                                   16, 0, 0);
}

__device__ __forceinline__ unsigned pkrtz(float a, float b) {
  union { fp16x2 h; unsigned u; } c;
  c.h = __builtin_amdgcn_cvt_pkrtz(a, b);
  return c.u;
}

// ---------------- f32 -> f16 cast (plain) ----------------
__global__ __launch_bounds__(256) void k_cast(const float* __restrict__ in,
                                              f16* __restrict__ out, int n4) {
  int stride = gridDim.x * blockDim.x;
  for (int i = blockIdx.x * blockDim.x + threadIdx.x; i < n4; i += stride) {
    float4 v = ((const float4*)in)[i];
    f16x4 o;
    o[0] = (f16)v.x; o[1] = (f16)v.y; o[2] = (f16)v.z; o[3] = (f16)v.w;
    ((f16x4*)out)[i] = o;
  }
}

// 4 independent cast jobs selected by blockIdx.y (equal sizes)
__global__ __launch_bounds__(256) void k_cast4(const float* __restrict__ s0, const float* __restrict__ s1,
                                               const float* __restrict__ s2, const float* __restrict__ s3,
                                               f16* __restrict__ d0, f16* __restrict__ d1,
                                               f16* __restrict__ d2, f16* __restrict__ d3, int n4) {
  const int which = blockIdx.y;
  const float* in = which == 0 ? s0 : which == 1 ? s1 : which == 2 ? s2 : s3;
  f16* out = which == 0 ? d0 : which == 1 ? d1 : which == 2 ? d2 : d3;
  int stride = gridDim.x * blockDim.x;
  for (int i = blockIdx.x * blockDim.x + threadIdx.x; i < n4; i += stride) {
    float4 v = ((const float4*)in)[i];
    f16x4 o;
    o[0] = (f16)v.x; o[1] = (f16)v.y; o[2] = (f16)v.z; o[3] = (f16)v.w;
    ((f16x4*)out)[i] = o;
  }
}

// 2 independent cast jobs selected by blockIdx.y
__global__ __launch_bounds__(256) void k_cast2w(const float* __restrict__ s0, const float* __restrict__ s1,
                                                f16* __restrict__ d0, f16* __restrict__ d1, int n4) {
  const int which = blockIdx.y;
  const float* in = which == 0 ? s0 : s1;
  f16* out = which == 0 ? d0 : d1;
  int stride = gridDim.x * blockDim.x;
  for (int i = blockIdx.x * blockDim.x + threadIdx.x; i < n4; i += stride) {
    float4 v = ((const float4*)in)[i];
    f16x4 o;
    o[0] = (f16)v.x; o[1] = (f16)v.y; o[2] = (f16)v.z; o[3] = (f16)v.w;
    ((f16x4*)out)[i] = o;
  }
}

// ---------------- V transpose: [BH][L][128] -> [BH][128][L] ----------------
__global__ __launch_bounds__(256) void k_transpose_v(const f16* __restrict__ vp,
                                                     f16* __restrict__ vt) {
  __shared__ __attribute__((aligned(16))) f16 tile[64][66];
  const int lt = blockIdx.x, dt = blockIdx.y, bh = blockIdx.z;
  const int t = threadIdx.x;
  const int r = t >> 3, c = 8 * (t & 7);
  const f16* src = vp + ((size_t)bh * 2048 + lt * 64) * 128 + dt * 64;
#pragma unroll
  for (int i = 0; i < 2; ++i) {
    union { f16x8 v; unsigned u[4]; } uu;
    uu.v = *(const f16x8*)&src[(size_t)(i * 32 + r) * 128 + c];
#pragma unroll
    for (int j = 0; j < 4; ++j)
      *(unsigned*)&tile[i * 32 + r][c + 2 * j] = uu.u[j];
  }
  __syncthreads();
  f16* dst = vt + ((size_t)bh * 128 + dt * 64) * 2048 + lt * 64;
#pragma unroll
  for (int i = 0; i < 2; ++i) {
    const int dr = i * 32 + r;
    f16x8 o;
#pragma unroll
    for (int e = 0; e < 8; ++e) o[e] = tile[c + e][dr];
    *(f16x8*)&dst[(size_t)dr * 2048 + c] = o;
  }
}

// ---------------- final fuse: out = f32(x1b) + p0 + p1 ----------------
__global__ __launch_bounds__(256) void k_fuseout(const f16* __restrict__ x1b,
                                                 const float* __restrict__ p0,
                                                 const float* __restrict__ p1,
                                                 float* __restrict__ out, int n4) {
  int stride = gridDim.x * blockDim.x;
  for (int i = blockIdx.x * blockDim.x + threadIdx.x; i < n4; i += stride) {
    float4 a = ((const float4*)p0)[i];
    float4 b = ((const float4*)p1)[i];
    f16x4 xb = ((const f16x4*)x1b)[i];
    float4 o;
    o.x = (float)xb[0] + a.x + b.x;
    o.y = (float)xb[1] + a.y + b.y;
    o.z = (float)xb[2] + a.z + b.z;
    o.w = (float)xb[3] + a.w + b.w;
    ((float4*)out)[i] = o;
  }
}

// ---------------- legacy 128x128 NT GEMM (kept for Wo) ----------------
// EPI 1: Wo -> outb = f16(res[idx] + C)
template <int EPI, int SPLITOUT, int BK>
__global__ __launch_bounds__(256, 4) void gemm_nt(const f16* __restrict__ A,
                                                  const f16* __restrict__ B,
                                                  int Kit, int ld, int N,
                                                  const float* __restrict__ res,
                                                  f16* __restrict__ outb) {
  constexpr int TSZ = 128 * BK;
  constexpr int CH  = 2048;
  constexpr int RPC = CH / BK;
  constexpr int NCH = 128 / RPC;
  constexpr int CW  = BK / 8;
  __shared__ __attribute__((aligned(16))) f16 As[TSZ];
  __shared__ __attribute__((aligned(16))) f16 Bs[TSZ];
  const int t = threadIdx.x;
  const int l = t & 63;
  const int w = t >> 6;
  const int wr = w >> 1, wc = w & 1;

  const int nwg = gridDim.x * gridDim.y;
  const int id = blockIdx.y * gridDim.x + blockIdx.x;
  const int sw = (id & 7) * (nwg >> 3) + (id >> 3);
  const int bn = sw % gridDim.x;
  const int bm = sw / gridDim.x;

  f32x4 acc[4][4] = {};

  const size_t aoff = (size_t)bm * 128 * ld;
  const size_t boff = (size_t)bn * 128 * ld;

  const int sr = t / CW;
  const int sc = 8 * (t % CW);
  const int lbase = w * 512;

  const int lr = l & 15, lq = l >> 4;
  const int nk = Kit / BK;
  for (int kt = 0; kt < nk; ++kt) {
    const size_t gbase = (size_t)kt * BK + (size_t)sr * ld + sc;
#pragma unroll
    for (int j = 0; j < NCH; ++j) {
      gload16(As + j * CH + lbase, A + aoff + (size_t)j * RPC * ld + gbase);
      gload16(Bs + j * CH + lbase, B + boff + (size_t)j * RPC * ld + gbase);
    }
    __syncthreads();
#pragma unroll
    for (int kk = 0; kk < BK / 32; ++kk) {
      f16x8 af[4], bfr[4];
#pragma unroll
      for (int m = 0; m < 4; ++m)
        af[m] = *(const f16x8*)&As[(wr * 64 + m * 16 + lr) * BK + kk * 32 + 8 * lq];
#pragma unroll
      for (int n = 0; n < 4; ++n)
        bfr[n] = *(const f16x8*)&Bs[(wc * 64 + n * 16 + lr) * BK + kk * 32 + 8 * lq];
#pragma unroll
      for (int m = 0; m < 4; ++m)
#pragma unroll
        for (int n = 0; n < 4; ++n)
          acc[m][n] = __builtin_amdgcn_mfma_f32_16x16x32_f16(af[m], bfr[n], acc[m][n], 0, 0, 0);
    }
    __syncthreads();
  }

#pragma unroll
  for (int m = 0; m < 4; ++m) {
#pragma unroll
    for (int r = 0; r < 4; ++r) {
      const int grow = bm * 128 + wr * 64 + m * 16 + lq * 4 + r;
#pragma unroll
      for (int n = 0; n < 4; ++n) {
        const int gcol = bn * 128 + wc * 64 + n * 16 + lr;
        const size_t idx = (size_t)grow * N + gcol;
        outb[idx] = (f16)(res[idx] + acc[m][n][r]);
      }
    }
  }
}

// ---------------- 256x256 pipelined NT GEMM (counted-vmcnt, 4 MFMA phases) ----------------
// C[M,N] = A[M,K] @ B[N,K]^T. 512 threads = 8 waves (2M x 4N), per-wave out 128x64.
// LDS: 2 buffers x (A 256x64 + B 256x64) f16 = 128 KiB, granule-XOR swizzle
// (phys granule = r*8 + (gc ^ (r&7)); staged via pre-swizzled global source).
// Schedule per tile t (buf b = t&1):
//   R1(af mh0 + bf, 16 ds_read) | BAR | MFMA 16 | BAR | MFMA 16 | BAR |
//   R2(af mh1, 8 ds_read) | lgkmcnt(0)+schedbar | BAR (all reads of buf b done)
//   stage tile t+2 -> buf b (8 gload_lds)  <- race-free: issued after read-complete barrier
//   MFMA 16 | BAR | MFMA 16 | vmcnt(8) | BAR   <- tile t+1's loads retired, t+2's in flight
// EPI 0: QKV split-output epilogue; EPI 2: Up bias+relu; EPI 3: Down f32 partial.
template <int EPI, int SPLITOUT>
__global__ __launch_bounds__(512, 2) void gemm8(const f16* __restrict__ A,
                                                const f16* __restrict__ B,
                                                int Kit, int ld, int N,
                                                const float* __restrict__ bias,
                                                float* __restrict__ outf,
                                                float* __restrict__ outf2,
                                                f16* __restrict__ outb,
                                                f16* __restrict__ outb_lo,
                                                f16* __restrict__ outv) {
  __shared__ __attribute__((aligned(16))) f16 As[2 * 16384];
  __shared__ __attribute__((aligned(16))) f16 Bs[2 * 16384];
  const int t = threadIdx.x;
  const int l = t & 63;
  const int w = t >> 6;
  const int wm = w >> 2, wn = w & 3;

  // XCD-aware bijective swizzle (nwg % 8 == 0 for all grids used)
  const int nwg = gridDim.x * gridDim.y;
  const int id = blockIdx.y * gridDim.x + blockIdx.x;
  const int sw = (id & 7) * (nwg >> 3) + (id >> 3);
  const int bn = sw % gridDim.x;
  const int bm = sw / gridDim.x;
  const int k0 = blockIdx.z * Kit;

  const size_t aoff = (size_t)(bm * 256) * ld + k0;
  const size_t boff = (size_t)(bn * 256) * ld + k0;

  // staging geometry: round j covers rows j*64 + (t>>3); thread's granule-in-row
  // is pre-swizzled so linear gload_lds dest matches the swizzled layout.
  const int rstage = t >> 3;
  const int gstage = (t & 7) ^ ((t >> 3) & 7);
  const int ldsb = (t >> 6) * 512;  // wave-uniform lds elem base per round chunk

  auto stage = [&](int tt, int b) {
    const size_t col = (size_t)tt * 64 + gstage * 8;
#pragma unroll
    for (int j = 0; j < 4; ++j) {
      const size_t grow = (size_t)(j * 64 + rstage) * ld + col;
      gload16(As + b * 16384 + j * 4096 + ldsb, A + aoff + grow);
      gload16(Bs + b * 16384 + j * 4096 + ldsb, B + boff + grow);
    }
  };

  f32x4 acc[8][4] = {};

  const int lr = l & 15, lq = l >> 4;
  const int x7 = lr & 7;
  const int nt = Kit >> 6;

  // prologue: tiles 0 and 1
  stage(0, 0);
  stage(1, 1);
  asm volatile("s_waitcnt vmcnt(8)" ::: "memory");  // tile 0 landed (mine); barrier -> all
  __builtin_amdgcn_s_barrier();

  for (int kt = 0; kt < nt; ++kt) {
    const int b = kt & 1;
    const f16* Ab = As + b * 16384;
    const f16* Bb = Bs + b * 16384;
    f16x8 af[4][2], bf[4][2];
    // R1: A m-half 0 + all B
#pragma unroll
    for (int m = 0; m < 4; ++m)
#pragma unroll
      for (int ks = 0; ks < 2; ++ks)
        af[m][ks] = *(const f16x8*)&Ab[((wm * 128 + m * 16 + lr) * 8 + ((ks * 4 + lq) ^ x7)) * 8];
#pragma unroll
    for (int n = 0; n < 4; ++n)
#pragma unroll
      for (int ks = 0; ks < 2; ++ks)
        bf[n][ks] = *(const f16x8*)&Bb[((wn * 64 + n * 16 + lr) * 8 + ((ks * 4 + lq) ^ x7)) * 8];
    __builtin_amdgcn_s_barrier();
    __builtin_amdgcn_s_setprio(1);
#pragma unroll
    for (int m = 0; m < 4; ++m)
#pragma unroll
      for (int n = 0; n < 2; ++n)
#pragma unroll
        for (int ks = 0; ks < 2; ++ks)
          acc[m][n] = __builtin_amdgcn_mfma_f32_16x16x32_f16(af[m][ks], bf[n][ks], acc[m][n], 0, 0, 0);
    __builtin_amdgcn_s_setprio(0);
    __builtin_amdgcn_s_barrier();
    __builtin_amdgcn_s_setprio(1);
#pragma unroll
    for (int m = 0; m < 4; ++m)
#pragma unroll
      for (int n = 2; n < 4; ++n)
#pragma unroll
        for (int ks = 0; ks < 2; ++ks)
          acc[m][n] = __builtin_amdgcn_mfma_f32_16x16x32_f16(af[m][ks], bf[n][ks], acc[m][n], 0, 0, 0);
    __builtin_amdgcn_s_setprio(0);
    __builtin_amdgcn_s_barrier();
    // R2: A m-half 1 (overwrites af)
#pragma unroll
    for (int m = 0; m < 4; ++m)
#pragma unroll
      for (int ks = 0; ks < 2; ++ks)
        af[m][ks] = *(const f16x8*)&Ab[((wm * 128 + 64 + m * 16 + lr) * 8 + ((ks * 4 + lq) ^ x7)) * 8];
    asm volatile("s_waitcnt lgkmcnt(0)" ::: "memory");
    __builtin_amdgcn_sched_barrier(0);
    __builtin_amdgcn_s_barrier();  // all waves' reads of buf b complete
    if (kt + 2 < nt) stage(kt + 2, b);  // safe: buf b fully consumed
    __builtin_amdgcn_s_setprio(1);
#pragma unroll
    for (int m = 0; m < 4; ++m)
#pragma unroll
      for (int n = 0; n < 2; ++n)
#pragma unroll
        for (int ks = 0; ks < 2; ++ks)
          acc[4 + m][n] = __builtin_amdgcn_mfma_f32_16x16x32_f16(af[m][ks], bf[n][ks], acc[4 + m][n], 0, 0, 0);
    __builtin_amdgcn_s_setprio(0);
    __builtin_amdgcn_s_barrier();
    __builtin_amdgcn_s_setprio(1);
#pragma unroll
    for (int m = 0; m < 4; ++m)
#pragma unroll
      for (int n = 2; n < 4; ++n)
#pragma unroll
        for (int ks = 0; ks < 2; ++ks)
          acc[4 + m][n] = __builtin_amdgcn_mfma_f32_16x16x32_f16(af[m][ks], bf[n][ks], acc[4 + m][n], 0, 0, 0);
    __builtin_amdgcn_s_setprio(0);
    // tile boundary: retire tile kt+1's loads; keep kt+2's in flight
    if (kt + 2 < nt) {
      asm volatile("s_waitcnt vmcnt(8)" ::: "memory");
    } else {
      asm volatile("s_waitcnt vmcnt(0)" ::: "memory");
    }
    __builtin_amdgcn_s_barrier();
  }

  const size_t QKS = (size_t)8 << 20;
#pragma unroll
  for (int m = 0; m < 8; ++m) {
#pragma unroll
    for (int r = 0; r < 4; ++r) {
      const int grow = bm * 256 + wm * 128 + m * 16 + lq * 4 + r;
#pragma unroll
      for (int n = 0; n < 4; ++n) {
        const int gcol = bn * 256 + wn * 64 + n * 16 + lr;
        const float v = acc[m][n][r];
        if constexpr (EPI == 0) {
          const int which = gcol >> 11;
          const int hcol = gcol & 2047;
          const int bb = grow >> 11, ll = grow & 2047;
          const int hh = hcol >> 7, dh = hcol & 127;
          const size_t idx = ((size_t)((bb * 16 + hh) * 2048 + ll) << 7) + dh;
          const f16 hv = (f16)v;
          if (which == 2) {
            outv[idx] = hv;
          } else {
            outb[which * QKS + idx] = hv;
            if constexpr (SPLITOUT) outb_lo[which * QKS + idx] = (f16)(v - (float)hv);
          }
        } else if constexpr (EPI == 2) {
          const size_t idx = (size_t)grow * N + gcol;
          outb[idx] = (f16)fmaxf(v + bias[gcol], 0.f);
        } else {
          const size_t idx = (size_t)grow * N + gcol;
          (blockIdx.z ? outf2 : outf)[idx] = v;
        }
      }
    }
  }
}

// ---------------- causal flash attention, 32x32 MFMA, swapped QK^T ----------------
__global__ __launch_bounds__(256) void k_attn(const f16* __restrict__ q_hi,
                                              const f16* __restrict__ q_lo,
                                              const f16* __restrict__ k_hi,
                                              const f16* __restrict__ k_lo,
                                              const f16* __restrict__ vtp,
                                              f16* __restrict__ op) {
  __shared__ __attribute__((aligned(16))) f16 Ks_hi[64 * 128];
  __shared__ __attribute__((aligned(16))) f16 Ks_lo[64 * 128];
  __shared__ __attribute__((aligned(16))) f16 Vs[128 * 64];
  const int t = threadIdx.x, l = t & 63, w = t >> 6;
  const int flat = (int)blockIdx.x;        // 0..511
  const int s_ = flat >> 5;                // 0..15
  const int bh = flat & 31;
  const int qb = (s_ < 8) ? (15 - s_) : (s_ - 8);  // complementary pairing
  const int q0 = qb * 128;
  const int lh = l >> 5, lm = l & 31;
  const int wrow0 = q0 + 32 * w;
  const int myrow = wrow0 + lm;

  const f16* qhp = q_hi + (size_t)bh * 2048 * 128;
  const f16* qlp = q_lo + (size_t)bh * 2048 * 128;
  const f16* khp = k_hi + (size_t)bh * 2048 * 128;
  const f16* klp = k_lo + (size_t)bh * 2048 * 128;
  const f16* vhp = vtp + (size_t)bh * 128 * 2048;

  const int krow = t >> 4, kg = t & 15;
  const int vrow = t >> 3, vg = t & 7;

  f16x8 aqh[8], aql[8];
#pragma unroll
  for (int c = 0; c < 8; ++c) {
    const size_t qi = (size_t)myrow * 128 + c * 16 + 8 * lh;
    aqh[c] = *(const f16x8*)&qhp[qi];
    aql[c] = *(const f16x8*)&qlp[qi];
  }

  f32x16 acc[4] = {};
  float mr = -1e30f, sr = 0.f;

  const int ntile = 2 * qb + 2;
  for (int kt = 0; kt < ntile; ++kt) {
    f16x8 tkh[4], tkl[4], tv[4];
#pragma unroll
    for (int i = 0; i < 4; ++i) {
      const size_t ki = (size_t)(kt * 64 + i * 16 + krow) * 128 + 8 * kg;
      tkh[i] = *(const f16x8*)&khp[ki];
      tkl[i] = *(const f16x8*)&klp[ki];
      tv[i] = *(const f16x8*)&vhp[(size_t)(i * 32 + vrow) * 2048 + kt * 64 + 8 * vg];
    }
    __syncthreads();
#pragma unroll
    for (int i = 0; i < 4; ++i) {
      const int kr = i * 16 + krow;
      const int g = kg ^ (kr & 7);
      *(f16x8*)&Ks_hi[kr * 128 + 8 * g] = tkh[i];
      *(f16x8*)&Ks_lo[kr * 128 + 8 * g] = tkl[i];
      const int vr = i * 32 + vrow;
      const int gv = vg ^ (vr & 7);
      *(f16x8*)&Vs[vr * 64 + 8 * gv] = tv[i];
    }
    __syncthreads();

    if (kt * 64 >= wrow0 + 32) continue;

    f32x16 s0, s1;
    __builtin_amdgcn_s_setprio(1);
    {
      f32x16 zh = {}, zl = {};
#pragma unroll
      for (int c = 0; c < 8; ++c) {
        const int g = (2 * c + lh) ^ (lm & 7);
        const f16x8 bh_ = *(const f16x8*)&Ks_hi[lm * 128 + 8 * g];
        const f16x8 bl_ = *(const f16x8*)&Ks_lo[lm * 128 + 8 * g];
        zh = __builtin_amdgcn_mfma_f32_32x32x16_f16(bh_, aqh[c], zh, 0, 0, 0);
        zl = __builtin_amdgcn_mfma_f32_32x32x16_f16(bh_, aql[c], zl, 0, 0, 0);
        zl = __builtin_amdgcn_mfma_f32_32x32x16_f16(bl_, aqh[c], zl, 0, 0, 0);
      }
      s0 = zh + zl;
    }
    {
      f32x16 zh = {}, zl = {};
#pragma unroll
      for (int c = 0; c < 8; ++c) {
        const int g = (2 * c + lh) ^ (lm & 7);
        const f16x8 bh_ = *(const f16x8*)&Ks_hi[(32 + lm) * 128 + 8 * g];
        const f16x8 bl_ = *(const f16x8*)&Ks_lo[(32 + lm) * 128 + 8 * g];
        zh = __builtin_amdgcn_mfma_f32_32x32x16_f16(bh_, aqh[c], zh, 0, 0, 0);
        zl = __builtin_amdgcn_mfma_f32_32x32x16_f16(bh_, aql[c], zl, 0, 0, 0);
        zl = __builtin_amdgcn_mfma_f32_32x32x16_f16(bl_, aqh[c], zl, 0, 0, 0);
      }
      s1 = zh + zl;
    }
    __builtin_amdgcn_s_setprio(0);

    if (kt * 64 + 63 > wrow0) {
#pragma unroll
      for (int j = 0; j < 16; ++j) {
        const int keyl = (j & 3) + 8 * (j >> 2) + 4 * lh;
        if (kt * 64 + keyl > myrow) s0[j] = -1e30f;
        if (kt * 64 + 32 + keyl > myrow) s1[j] = -1e30f;
      }
    }

    float m = -1e30f;
#pragma unroll
    for (int j = 0; j < 16; ++j) m = fmaxf(m, fmaxf(s0[j], s1[j]));
    m = fmaxf(m, __shfl_xor(m, 32));
    if (__any(m > mr + 8.f)) {
      const float mnew = fmaxf(mr, m);
      const float sc = __expf(mr - mnew);
      mr = mnew;
      sr *= sc;
#pragma unroll
      for (int j = 0; j < 16; ++j) {
        const float scj = __shfl(sc, (j & 3) + 8 * (j >> 2) + 4 * lh);
#pragma unroll
        for (int ct = 0; ct < 4; ++ct) acc[ct][j] *= scj;
      }
    }
    float p0v[16], p1v[16];
    float ts = 0.f;
#pragma unroll
    for (int j = 0; j < 16; ++j) {
      p0v[j] = __expf(s0[j] - mr);
      p1v[j] = __expf(s1[j] - mr);
      ts += p0v[j] + p1v[j];
    }
    sr += ts + __shfl_xor(ts, 32);

    unsigned u[16];
#pragma unroll
    for (int m2 = 0; m2 < 8; ++m2) {
      u[m2] = pkrtz(p0v[2 * m2], p0v[2 * m2 + 1]);
      u[8 + m2] = pkrtz(p1v[2 * m2], p1v[2 * m2 + 1]);
    }
    unsigned ys[8];
#pragma unroll
    for (int m2 = 0; m2 < 8; ++m2) {
      const int q_ = m2 >> 1, h_ = m2 & 1;
      const unsigned xs = lh ? u[4 * q_ + h_] : u[4 * q_ + 2 + h_];
      ys[m2] = __shfl_xor(xs, 32);
    }
    f16x8 pf[4];
#pragma unroll
    for (int kk = 0; kk < 4; ++kk) {
      union { u32x4 u4; f16x8 h8; } cv;
      if (lh == 0) {
        cv.u4[0] = u[4 * kk];     cv.u4[1] = u[4 * kk + 1];
        cv.u4[2] = ys[2 * kk];    cv.u4[3] = ys[2 * kk + 1];
      } else {
        cv.u4[0] = ys[2 * kk];    cv.u4[1] = ys[2 * kk + 1];
        cv.u4[2] = u[4 * kk + 2]; cv.u4[3] = u[4 * kk + 3];
      }
      pf[kk] = cv.h8;
    }

    __builtin_amdgcn_s_setprio(1);
#pragma unroll
    for (int ct = 0; ct < 4; ++ct) {
      const int dcol = ct * 32 + lm;
#pragma unroll
      for (int kk = 0; kk < 4; ++kk) {
        const int gv = (2 * kk + lh) ^ (dcol & 7);
        const f16x8 bv = *(const f16x8*)&Vs[dcol * 64 + 8 * gv];
        acc[ct] = __builtin_amdgcn_mfma_f32_32x32x16_f16(pf[kk], bv, acc[ct], 0, 0, 0);
      }
    }
    __builtin_amdgcn_s_setprio(0);
  }

  const int bb = bh >> 4, hh = bh & 15;
  const float inv = 1.f / sr;
#pragma unroll
  for (int j = 0; j < 16; ++j) {
    const int rl = (j & 3) + 8 * (j >> 2) + 4 * lh;
    const float invj = __shfl(inv, rl);
    const size_t row = (size_t)(bb * 2048 + wrow0 + rl);
#pragma unroll
    for (int ct = 0; ct < 4; ++ct)
      op[row * 2048 + hh * 128 + ct * 32 + lm] = (f16)(acc[ct][j] * invj);
  }
}

extern "C" void kernel_launch(void* const* d_in, const int* in_sizes, int n_in,
                              void* d_out, int out_size, void* d_ws, size_t ws_size,
                              hipStream_t stream) {
  const float* x   = (const float*)d_in[0];
  const float* Wq  = (const float*)d_in[2];
  const float* Wk  = (const float*)d_in[3];
  const float* Wv  = (const float*)d_in[4];
  const float* Wo  = (const float*)d_in[5];
  const float* Wup = (const float*)d_in[6];
  const float* bup = (const float*)d_in[7];
  const float* Wdn = (const float*)d_in[8];
  float* out = (float*)d_out;

  const size_t M1 = 1u << 20;
  f16* W = (f16*)d_ws;
  // workspace layout (units of M1 f16 elems); overlays reuse dead regions:
  //  [0..8)    x_hi (dead after QKV gemm)     -> x1b overlay (live to fuseout)
  //  [8..20)   wqkv_hi (dead after QKV)
  //  [20..24)  wo_hi (dead after Wo)
  //  [24..40)  wup_hi (dead after Up)         -> p0 overlay (8M floats)
  //  [40..56)  wdn_hi (live to Down)
  //  [56..88)  q_hi/k_hi/q_lo/k_lo (dead after attn) -> hb overlay [56..88)
  //  [88..96)  vp (V proj; attn out; dead after Wo)  -> p1 overlay [88..104)
  //  [96..104) vtb (dead after attn)
  f16* x_hi    = W + 0 * M1;
  f16* wqkv_hi = W + 8 * M1;
  f16* wo_hi   = W + 20 * M1;
  f16* wup_hi  = W + 24 * M1;
  f16* wdn_hi  = W + 40 * M1;
  f16* q_hi    = W + 56 * M1;
  f16* q_lo    = W + 72 * M1;
  f16* vp      = W + 88 * M1;
  f16* vtb     = W + 96 * M1;
  // overlays (checked against live sets per stage):
  f16* x1b   = x_hi;
  float* p0  = (float*)(W + 24 * M1);
  f16* hb    = W + 56 * M1;
  float* p1  = (float*)(W + 88 * M1);
  f16* attno = vp;
  if (ws_size < (size_t)104 * M1 * sizeof(f16)) return;  // 208 MB

  auto cg = [](size_t n4) { size_t g = (n4 + 255) / 256; return (unsigned)(g > 2048 ? 2048 : g); };
  dim3 b256(256);
  dim3 b512(512);
  k_cast<<<cg(2 * M1), b256, 0, stream>>>(x, x_hi, (int)(2 * M1));
  k_cast4<<<dim3(cg(1 * M1), 4), b256, 0, stream>>>(
      Wq, Wk, Wv, Wo,
      wqkv_hi, wqkv_hi + 4 * M1, wqkv_hi + 8 * M1, wo_hi, (int)(1 * M1));
  k_cast2w<<<dim3(cg(4 * M1), 2), b256, 0, stream>>>(
      Wup, Wdn, wup_hi, wdn_hi, (int)(4 * M1));

  // fused Q+K+V projection: 256x256 pipelined, split (hi+lo) OUTPUT for Q,K.
  gemm8<0, 1><<<dim3(24, 16), b512, 0, stream>>>(
      x_hi, wqkv_hi, 2048, 2048, 6144,
      nullptr, nullptr, nullptr, q_hi, q_lo, vp);
  k_transpose_v<<<dim3(32, 2, 32), b256, 0, stream>>>(vp, vtb);
  k_attn<<<dim3(512), b256, 0, stream>>>(
      q_hi, q_lo, q_hi + 8 * M1, q_lo + 8 * M1, vtb, attno);
  // Wo projection + residual -> x1b (f16), legacy 128^2 kernel
  gemm_nt<1, 0, 64><<<dim3(16, 32), b256, 0, stream>>>(
      attno, wo_hi, 2048, 2048, 2048, x, x1b);
  // Up + bias + relu -> hb
  gemm8<2, 0><<<dim3(32, 16), b512, 0, stream>>>(
      x1b, wup_hi, 2048, 2048, 8192,
      bup, nullptr, nullptr, hb, nullptr, nullptr);
  // Down, K split 2x -> f32 partials
  gemm8<3, 0><<<dim3(8, 16, 2), b512, 0, stream>>>(
      hb, wdn_hi, 4096, 8192, 2048,
      nullptr, p0, p1, nullptr, nullptr, nullptr);
  // out = f32(x1b) + p0 + p1
  k_fuseout<<<2048, b256, 0, stream>>>(x1b, p0, p1, out, (int)(2 * M1));
}

// Round 16
// 710.496 us; speedup vs baseline: 1.3597x; 1.0175x over previous
//
#include <hip/hip_runtime.h>
#include <stdint.h>

typedef _Float16 f16;
typedef __attribute__((ext_vector_type(8))) _Float16 f16x8;
typedef __attribute__((ext_vector_type(4))) _Float16 f16x4;
typedef __attribute__((ext_vector_type(2))) __fp16 fp16x2;
typedef __attribute__((ext_vector_type(4))) float f32x4;
typedef __attribute__((ext_vector_type(16))) float f32x16;
typedef __attribute__((ext_vector_type(4))) unsigned u32x4;

// async global->LDS, 16B per lane. LDS dest is wave-uniform base (+lane*16 in HW).
__device__ __forceinline__ void gload16(void* lds, const void* gc) {
  void* g = const_cast<void*>(gc);
  __builtin_amdgcn_global_load_lds((__attribute__((address_space(1))) void*)g,
                                   (__attribute__((address_space(3))) void*)lds,
                                   16, 0, 0);
}

__device__ __forceinline__ unsigned pkrtz(float a, float b) {
  union { fp16x2 h; unsigned u; } c;
  c.h = __builtin_amdgcn_cvt_pkrtz(a, b);
  return c.u;
}

// ---------------- f32 -> f16 cast (plain) ----------------
__global__ __launch_bounds__(256) void k_cast(const float* __restrict__ in,
                                              f16* __restrict__ out, int n4) {
  int stride = gridDim.x * blockDim.x;
  for (int i = blockIdx.x * blockDim.x + threadIdx.x; i < n4; i += stride) {
    float4 v = ((const float4*)in)[i];
    f16x4 o;
    o[0] = (f16)v.x; o[1] = (f16)v.y; o[2] = (f16)v.z; o[3] = (f16)v.w;
    ((f16x4*)out)[i] = o;
  }
}

// 4 independent cast jobs selected by blockIdx.y (equal sizes)
__global__ __launch_bounds__(256) void k_cast4(const float* __restrict__ s0, const float* __restrict__ s1,
                                               const float* __restrict__ s2, const float* __restrict__ s3,
                                               f16* __restrict__ d0, f16* __restrict__ d1,
                                               f16* __restrict__ d2, f16* __restrict__ d3, int n4) {
  const int which = blockIdx.y;
  const float* in = which == 0 ? s0 : which == 1 ? s1 : which == 2 ? s2 : s3;
  f16* out = which == 0 ? d0 : which == 1 ? d1 : which == 2 ? d2 : d3;
  int stride = gridDim.x * blockDim.x;
  for (int i = blockIdx.x * blockDim.x + threadIdx.x; i < n4; i += stride) {
    float4 v = ((const float4*)in)[i];
    f16x4 o;
    o[0] = (f16)v.x; o[1] = (f16)v.y; o[2] = (f16)v.z; o[3] = (f16)v.w;
    ((f16x4*)out)[i] = o;
  }
}

// 2 independent cast jobs selected by blockIdx.y
__global__ __launch_bounds__(256) void k_cast2w(const float* __restrict__ s0, const float* __restrict__ s1,
                                                f16* __restrict__ d0, f16* __restrict__ d1, int n4) {
  const int which = blockIdx.y;
  const float* in = which == 0 ? s0 : s1;
  f16* out = which == 0 ? d0 : d1;
  int stride = gridDim.x * blockDim.x;
  for (int i = blockIdx.x * blockDim.x + threadIdx.x; i < n4; i += stride) {
    float4 v = ((const float4*)in)[i];
    f16x4 o;
    o[0] = (f16)v.x; o[1] = (f16)v.y; o[2] = (f16)v.z; o[3] = (f16)v.w;
    ((f16x4*)out)[i] = o;
  }
}

// ---------------- V transpose: [BH][L][128] -> [BH][128][L] ----------------
__global__ __launch_bounds__(256) void k_transpose_v(const f16* __restrict__ vp,
                                                     f16* __restrict__ vt) {
  __shared__ __attribute__((aligned(16))) f16 tile[64][66];
  const int lt = blockIdx.x, dt = blockIdx.y, bh = blockIdx.z;
  const int t = threadIdx.x;
  const int r = t >> 3, c = 8 * (t & 7);
  const f16* src = vp + ((size_t)bh * 2048 + lt * 64) * 128 + dt * 64;
#pragma unroll
  for (int i = 0; i < 2; ++i) {
    union { f16x8 v; unsigned u[4]; } uu;
    uu.v = *(const f16x8*)&src[(size_t)(i * 32 + r) * 128 + c];
#pragma unroll
    for (int j = 0; j < 4; ++j)
      *(unsigned*)&tile[i * 32 + r][c + 2 * j] = uu.u[j];
  }
  __syncthreads();
  f16* dst = vt + ((size_t)bh * 128 + dt * 64) * 2048 + lt * 64;
#pragma unroll
  for (int i = 0; i < 2; ++i) {
    const int dr = i * 32 + r;
    f16x8 o;
#pragma unroll
    for (int e = 0; e < 8; ++e) o[e] = tile[c + e][dr];
    *(f16x8*)&dst[(size_t)dr * 2048 + c] = o;
  }
}

// ---------------- final fuse: out = f32(x1b) + p0 + p1 ----------------
__global__ __launch_bounds__(256) void k_fuseout(const f16* __restrict__ x1b,
                                                 const float* __restrict__ p0,
                                                 const float* __restrict__ p1,
                                                 float* __restrict__ out, int n4) {
  int stride = gridDim.x * blockDim.x;
  for (int i = blockIdx.x * blockDim.x + threadIdx.x; i < n4; i += stride) {
    float4 a = ((const float4*)p0)[i];
    float4 b = ((const float4*)p1)[i];
    f16x4 xb = ((const f16x4*)x1b)[i];
    float4 o;
    o.x = (float)xb[0] + a.x + b.x;
    o.y = (float)xb[1] + a.y + b.y;
    o.z = (float)xb[2] + a.z + b.z;
    o.w = (float)xb[3] + a.w + b.w;
    ((float4*)out)[i] = o;
  }
}

// ---------------- legacy 128x128 NT GEMM (kept for Wo) ----------------
// EPI 1: Wo -> outb = f16(res[idx] + C)
template <int EPI, int SPLITOUT, int BK>
__global__ __launch_bounds__(256, 4) void gemm_nt(const f16* __restrict__ A,
                                                  const f16* __restrict__ B,
                                                  int Kit, int ld, int N,
                                                  const float* __restrict__ res,
                                                  f16* __restrict__ outb) {
  constexpr int TSZ = 128 * BK;
  constexpr int CH  = 2048;
  constexpr int RPC = CH / BK;
  constexpr int NCH = 128 / RPC;
  constexpr int CW  = BK / 8;
  __shared__ __attribute__((aligned(16))) f16 As[TSZ];
  __shared__ __attribute__((aligned(16))) f16 Bs[TSZ];
  const int t = threadIdx.x;
  const int l = t & 63;
  const int w = t >> 6;
  const int wr = w >> 1, wc = w & 1;

  const int nwg = gridDim.x * gridDim.y;
  const int id = blockIdx.y * gridDim.x + blockIdx.x;
  const int sw = (id & 7) * (nwg >> 3) + (id >> 3);
  const int bn = sw % gridDim.x;
  const int bm = sw / gridDim.x;

  f32x4 acc[4][4] = {};

  const size_t aoff = (size_t)bm * 128 * ld;
  const size_t boff = (size_t)bn * 128 * ld;

  const int sr = t / CW;
  const int sc = 8 * (t % CW);
  const int lbase = w * 512;

  const int lr = l & 15, lq = l >> 4;
  const int nk = Kit / BK;
  for (int kt = 0; kt < nk; ++kt) {
    const size_t gbase = (size_t)kt * BK + (size_t)sr * ld + sc;
#pragma unroll
    for (int j = 0; j < NCH; ++j) {
      gload16(As + j * CH + lbase, A + aoff + (size_t)j * RPC * ld + gbase);
      gload16(Bs + j * CH + lbase, B + boff + (size_t)j * RPC * ld + gbase);
    }
    __syncthreads();
#pragma unroll
    for (int kk = 0; kk < BK / 32; ++kk) {
      f16x8 af[4], bfr[4];
#pragma unroll
      for (int m = 0; m < 4; ++m)
        af[m] = *(const f16x8*)&As[(wr * 64 + m * 16 + lr) * BK + kk * 32 + 8 * lq];
#pragma unroll
      for (int n = 0; n < 4; ++n)
        bfr[n] = *(const f16x8*)&Bs[(wc * 64 + n * 16 + lr) * BK + kk * 32 + 8 * lq];
#pragma unroll
      for (int m = 0; m < 4; ++m)
#pragma unroll
        for (int n = 0; n < 4; ++n)
          acc[m][n] = __builtin_amdgcn_mfma_f32_16x16x32_f16(af[m], bfr[n], acc[m][n], 0, 0, 0);
    }
    __syncthreads();
  }

#pragma unroll
  for (int m = 0; m < 4; ++m) {
#pragma unroll
    for (int r = 0; r < 4; ++r) {
      const int grow = bm * 128 + wr * 64 + m * 16 + lq * 4 + r;
#pragma unroll
      for (int n = 0; n < 4; ++n) {
        const int gcol = bn * 128 + wc * 64 + n * 16 + lr;
        const size_t idx = (size_t)grow * N + gcol;
        outb[idx] = (f16)(res[idx] + acc[m][n][r]);
      }
    }
  }
}

// ---------------- 256x256 BK=32 4-buffer-ring pipelined NT GEMM ----------------
// 512 threads = 8 waves (2M x 4N), per-wave out 128x64. ONE barrier per K-tile.
// LDS ring: 4 bufs x (A 256x32 + B 256x32) f16 = 128 KiB. Granule swizzle
// g' = g ^ (r&3) ^ ((r>>2)&3) (involution; applied on staging SOURCE col and
// on fragment reads -> ~2-way banks, and gload_lds dest stays linear).
// Per tile t (buf = t&3): issue 12 ds_read -> stage(t+3 -> buf (t-1)&3, safe:
// that buf's reads were consumed by tile t-1's MFMAs before the boundary
// barrier) -> 32 MFMA (compiler-counted lgkm waits) -> vmcnt(8 keeps t+2/t+3
// in flight, retires t+1) -> s_barrier.
template <int EPI, int SPLITOUT>
__global__ __launch_bounds__(512, 2) void gemm8(const f16* __restrict__ A,
                                                const f16* __restrict__ B,
                                                int Kit, int ld, int N,
                                                const float* __restrict__ bias,
                                                float* __restrict__ outf,
                                                float* __restrict__ outf2,
                                                f16* __restrict__ outb,
                                                f16* __restrict__ outb_lo,
                                                f16* __restrict__ outv) {
  __shared__ __attribute__((aligned(16))) f16 As[4 * 8192];
  __shared__ __attribute__((aligned(16))) f16 Bs[4 * 8192];
  const int t = threadIdx.x;
  const int l = t & 63;
  const int w = t >> 6;
  const int wm = w >> 2, wn = w & 3;

  // XCD-aware bijective swizzle (nwg % 8 == 0 for all grids used)
  const int nwg = gridDim.x * gridDim.y;
  const int id = blockIdx.y * gridDim.x + blockIdx.x;
  const int sw = (id & 7) * (nwg >> 3) + (id >> 3);
  const int bn = sw % gridDim.x;
  const int bm = sw / gridDim.x;
  const int k0 = blockIdx.z * Kit;

  const size_t aoff = (size_t)(bm * 256) * ld + k0;
  const size_t boff = (size_t)(bn * 256) * ld + k0;

  // staging: thread t covers LDS slot t (row t>>2, granule t&3) per 128-row round;
  // source col granule pre-swizzled (j-invariant since 128 % 16 == 0).
  const int r0 = t >> 2;
  const int gsw = (t & 3) ^ (r0 & 3) ^ ((r0 >> 2) & 3);
  const int ldsb = (t >> 6) * 512;  // wave-uniform elem base (lane*16B implicit)

  auto stage = [&](int tt, int b) {
    const size_t col = (size_t)tt * 32 + gsw * 8;
#pragma unroll
    for (int j = 0; j < 2; ++j) {
      const size_t grow = (size_t)(j * 128 + r0) * ld + col;
      gload16(As + b * 8192 + j * 4096 + ldsb, A + aoff + grow);
      gload16(Bs + b * 8192 + j * 4096 + ldsb, B + boff + grow);
    }
  };

  f32x4 acc[8][4] = {};

  const int lr = l & 15, lq = l >> 4;
  const int xg = (lr & 3) ^ ((lr >> 2) & 3);  // frag-row granule XOR (m/wave-invariant)
  const int nt = Kit >> 5;

  // prologue: tiles 0..2 staged; tile 0 landed before loop
  stage(0, 0);
  stage(1, 1);
  stage(2, 2);
  asm volatile("s_waitcnt vmcnt(8)" ::: "memory");
  __builtin_amdgcn_s_barrier();

  for (int kt = 0; kt < nt; ++kt) {
    const int b = kt & 3;
    const f16* Ab = As + b * 8192;
    const f16* Bb = Bs + b * 8192;
    f16x8 af[8], bf[4];
#pragma unroll
    for (int m = 0; m < 8; ++m) {
      const int row = wm * 128 + m * 16 + lr;
      af[m] = *(const f16x8*)&Ab[row * 32 + (lq ^ xg) * 8];
    }
#pragma unroll
    for (int n = 0; n < 4; ++n) {
      const int row = wn * 64 + n * 16 + lr;
      bf[n] = *(const f16x8*)&Bb[row * 32 + (lq ^ xg) * 8];
    }
    if (kt + 3 < nt) stage(kt + 3, (kt + 3) & 3);
    __builtin_amdgcn_s_setprio(1);
#pragma unroll
    for (int m = 0; m < 8; ++m)
#pragma unroll
      for (int n = 0; n < 4; ++n)
        acc[m][n] = __builtin_amdgcn_mfma_f32_16x16x32_f16(af[m], bf[n], acc[m][n], 0, 0, 0);
    __builtin_amdgcn_s_setprio(0);
    // retire tile kt+1's stage ops; keep kt+2 (and kt+3 if staged) in flight
    if (kt + 3 < nt) {
      asm volatile("s_waitcnt vmcnt(8)" ::: "memory");
    } else if (kt + 2 < nt) {
      asm volatile("s_waitcnt vmcnt(4)" ::: "memory");
    } else {
      asm volatile("s_waitcnt vmcnt(0)" ::: "memory");
    }
    __builtin_amdgcn_s_barrier();
  }

  const size_t QKS = (size_t)8 << 20;
#pragma unroll
  for (int m = 0; m < 8; ++m) {
#pragma unroll
    for (int r = 0; r < 4; ++r) {
      const int grow = bm * 256 + wm * 128 + m * 16 + lq * 4 + r;
#pragma unroll
      for (int n = 0; n < 4; ++n) {
        const int gcol = bn * 256 + wn * 64 + n * 16 + lr;
        const float v = acc[m][n][r];
        if constexpr (EPI == 0) {
          const int which = gcol >> 11;
          const int hcol = gcol & 2047;
          const int bb = grow >> 11, ll = grow & 2047;
          const int hh = hcol >> 7, dh = hcol & 127;
          const size_t idx = ((size_t)((bb * 16 + hh) * 2048 + ll) << 7) + dh;
          const f16 hv = (f16)v;
          if (which == 2) {
            outv[idx] = hv;
          } else {
            outb[which * QKS + idx] = hv;
            if constexpr (SPLITOUT) outb_lo[which * QKS + idx] = (f16)(v - (float)hv);
          }
        } else if constexpr (EPI == 2) {
          const size_t idx = (size_t)grow * N + gcol;
          outb[idx] = (f16)fmaxf(v + bias[gcol], 0.f);
        } else {
          const size_t idx = (size_t)grow * N + gcol;
          (blockIdx.z ? outf2 : outf)[idx] = v;
        }
      }
    }
  }
}

// ---------------- causal flash attention, 32x32 MFMA, swapped QK^T ----------------
__global__ __launch_bounds__(256) void k_attn(const f16* __restrict__ q_hi,
                                              const f16* __restrict__ q_lo,
                                              const f16* __restrict__ k_hi,
                                              const f16* __restrict__ k_lo,
                                              const f16* __restrict__ vtp,
                                              f16* __restrict__ op) {
  __shared__ __attribute__((aligned(16))) f16 Ks_hi[64 * 128];
  __shared__ __attribute__((aligned(16))) f16 Ks_lo[64 * 128];
  __shared__ __attribute__((aligned(16))) f16 Vs[128 * 64];
  const int t = threadIdx.x, l = t & 63, w = t >> 6;
  const int flat = (int)blockIdx.x;        // 0..511
  const int s_ = flat >> 5;                // 0..15
  const int bh = flat & 31;
  const int qb = (s_ < 8) ? (15 - s_) : (s_ - 8);  // complementary pairing
  const int q0 = qb * 128;
  const int lh = l >> 5, lm = l & 31;
  const int wrow0 = q0 + 32 * w;
  const int myrow = wrow0 + lm;

  const f16* qhp = q_hi + (size_t)bh * 2048 * 128;
  const f16* qlp = q_lo + (size_t)bh * 2048 * 128;
  const f16* khp = k_hi + (size_t)bh * 2048 * 128;
  const f16* klp = k_lo + (size_t)bh * 2048 * 128;
  const f16* vhp = vtp + (size_t)bh * 128 * 2048;

  const int krow = t >> 4, kg = t & 15;
  const int vrow = t >> 3, vg = t & 7;

  f16x8 aqh[8], aql[8];
#pragma unroll
  for (int c = 0; c < 8; ++c) {
    const size_t qi = (size_t)myrow * 128 + c * 16 + 8 * lh;
    aqh[c] = *(const f16x8*)&qhp[qi];
    aql[c] = *(const f16x8*)&qlp[qi];
  }

  f32x16 acc[4] = {};
  float mr = -1e30f, sr = 0.f;

  const int ntile = 2 * qb + 2;
  for (int kt = 0; kt < ntile; ++kt) {
    f16x8 tkh[4], tkl[4], tv[4];
#pragma unroll
    for (int i = 0; i < 4; ++i) {
      const size_t ki = (size_t)(kt * 64 + i * 16 + krow) * 128 + 8 * kg;
      tkh[i] = *(const f16x8*)&khp[ki];
      tkl[i] = *(const f16x8*)&klp[ki];
      tv[i] = *(const f16x8*)&vhp[(size_t)(i * 32 + vrow) * 2048 + kt * 64 + 8 * vg];
    }
    __syncthreads();
#pragma unroll
    for (int i = 0; i < 4; ++i) {
      const int kr = i * 16 + krow;
      const int g = kg ^ (kr & 7);
      *(f16x8*)&Ks_hi[kr * 128 + 8 * g] = tkh[i];
      *(f16x8*)&Ks_lo[kr * 128 + 8 * g] = tkl[i];
      const int vr = i * 32 + vrow;
      const int gv = vg ^ (vr & 7);
      *(f16x8*)&Vs[vr * 64 + 8 * gv] = tv[i];
    }
    __syncthreads();

    if (kt * 64 >= wrow0 + 32) continue;

    f32x16 s0, s1;
    __builtin_amdgcn_s_setprio(1);
    {
      f32x16 zh = {}, zl = {};
#pragma unroll
      for (int c = 0; c < 8; ++c) {
        const int g = (2 * c + lh) ^ (lm & 7);
        const f16x8 bh_ = *(const f16x8*)&Ks_hi[lm * 128 + 8 * g];
        const f16x8 bl_ = *(const f16x8*)&Ks_lo[lm * 128 + 8 * g];
        zh = __builtin_amdgcn_mfma_f32_32x32x16_f16(bh_, aqh[c], zh, 0, 0, 0);
        zl = __builtin_amdgcn_mfma_f32_32x32x16_f16(bh_, aql[c], zl, 0, 0, 0);
        zl = __builtin_amdgcn_mfma_f32_32x32x16_f16(bl_, aqh[c], zl, 0, 0, 0);
      }
      s0 = zh + zl;
    }
    {
      f32x16 zh = {}, zl = {};
#pragma unroll
      for (int c = 0; c < 8; ++c) {
        const int g = (2 * c + lh) ^ (lm & 7);
        const f16x8 bh_ = *(const f16x8*)&Ks_hi[(32 + lm) * 128 + 8 * g];
        const f16x8 bl_ = *(const f16x8*)&Ks_lo[(32 + lm) * 128 + 8 * g];
        zh = __builtin_amdgcn_mfma_f32_32x32x16_f16(bh_, aqh[c], zh, 0, 0, 0);
        zl = __builtin_amdgcn_mfma_f32_32x32x16_f16(bh_, aql[c], zl, 0, 0, 0);
        zl = __builtin_amdgcn_mfma_f32_32x32x16_f16(bl_, aqh[c], zl, 0, 0, 0);
      }
      s1 = zh + zl;
    }
    __builtin_amdgcn_s_setprio(0);

    if (kt * 64 + 63 > wrow0) {
#pragma unroll
      for (int j = 0; j < 16; ++j) {
        const int keyl = (j & 3) + 8 * (j >> 2) + 4 * lh;
        if (kt * 64 + keyl > myrow) s0[j] = -1e30f;
        if (kt * 64 + 32 + keyl > myrow) s1[j] = -1e30f;
      }
    }

    float m = -1e30f;
#pragma unroll
    for (int j = 0; j < 16; ++j) m = fmaxf(m, fmaxf(s0[j], s1[j]));
    m = fmaxf(m, __shfl_xor(m, 32));
    if (__any(m > mr + 8.f)) {
      const float mnew = fmaxf(mr, m);
      const float sc = __expf(mr - mnew);
      mr = mnew;
      sr *= sc;
#pragma unroll
      for (int j = 0; j < 16; ++j) {
        const float scj = __shfl(sc, (j & 3) + 8 * (j >> 2) + 4 * lh);
#pragma unroll
        for (int ct = 0; ct < 4; ++ct) acc[ct][j] *= scj;
      }
    }
    float p0v[16], p1v[16];
    float ts = 0.f;
#pragma unroll
    for (int j = 0; j < 16; ++j) {
      p0v[j] = __expf(s0[j] - mr);
      p1v[j] = __expf(s1[j] - mr);
      ts += p0v[j] + p1v[j];
    }
    sr += ts + __shfl_xor(ts, 32);

    unsigned u[16];
#pragma unroll
    for (int m2 = 0; m2 < 8; ++m2) {
      u[m2] = pkrtz(p0v[2 * m2], p0v[2 * m2 + 1]);
      u[8 + m2] = pkrtz(p1v[2 * m2], p1v[2 * m2 + 1]);
    }
    unsigned ys[8];
#pragma unroll
    for (int m2 = 0; m2 < 8; ++m2) {
      const int q_ = m2 >> 1, h_ = m2 & 1;
      const unsigned xs = lh ? u[4 * q_ + h_] : u[4 * q_ + 2 + h_];
      ys[m2] = __shfl_xor(xs, 32);
    }
    f16x8 pf[4];
#pragma unroll
    for (int kk = 0; kk < 4; ++kk) {
      union { u32x4 u4; f16x8 h8; } cv;
      if (lh == 0) {
        cv.u4[0] = u[4 * kk];     cv.u4[1] = u[4 * kk + 1];
        cv.u4[2] = ys[2 * kk];    cv.u4[3] = ys[2 * kk + 1];
      } else {
        cv.u4[0] = ys[2 * kk];    cv.u4[1] = ys[2 * kk + 1];
        cv.u4[2] = u[4 * kk + 2]; cv.u4[3] = u[4 * kk + 3];
      }
      pf[kk] = cv.h8;
    }

    __builtin_amdgcn_s_setprio(1);
#pragma unroll
    for (int ct = 0; ct < 4; ++ct) {
      const int dcol = ct * 32 + lm;
#pragma unroll
      for (int kk = 0; kk < 4; ++kk) {
        const int gv = (2 * kk + lh) ^ (dcol & 7);
        const f16x8 bv = *(const f16x8*)&Vs[dcol * 64 + 8 * gv];
        acc[ct] = __builtin_amdgcn_mfma_f32_32x32x16_f16(pf[kk], bv, acc[ct], 0, 0, 0);
      }
    }
    __builtin_amdgcn_s_setprio(0);
  }

  const int bb = bh >> 4, hh = bh & 15;
  const float inv = 1.f / sr;
#pragma unroll
  for (int j = 0; j < 16; ++j) {
    const int rl = (j & 3) + 8 * (j >> 2) + 4 * lh;
    const float invj = __shfl(inv, rl);
    const size_t row = (size_t)(bb * 2048 + wrow0 + rl);
#pragma unroll
    for (int ct = 0; ct < 4; ++ct)
      op[row * 2048 + hh * 128 + ct * 32 + lm] = (f16)(acc[ct][j] * invj);
  }
}

extern "C" void kernel_launch(void* const* d_in, const int* in_sizes, int n_in,
                              void* d_out, int out_size, void* d_ws, size_t ws_size,
                              hipStream_t stream) {
  const float* x   = (const float*)d_in[0];
  const float* Wq  = (const float*)d_in[2];
  const float* Wk  = (const float*)d_in[3];
  const float* Wv  = (const float*)d_in[4];
  const float* Wo  = (const float*)d_in[5];
  const float* Wup = (const float*)d_in[6];
  const float* bup = (const float*)d_in[7];
  const float* Wdn = (const float*)d_in[8];
  float* out = (float*)d_out;

  const size_t M1 = 1u << 20;
  f16* W = (f16*)d_ws;
  // workspace layout (units of M1 f16 elems); overlays reuse dead regions:
  //  [0..8)    x_hi (dead after QKV gemm)     -> x1b overlay (live to fuseout)
  //  [8..20)   wqkv_hi (dead after QKV)
  //  [20..24)  wo_hi (dead after Wo)
  //  [24..40)  wup_hi (dead after Up)         -> p0 overlay (8M floats)
  //  [40..56)  wdn_hi (live to Down)
  //  [56..88)  q_hi/k_hi/q_lo/k_lo (dead after attn) -> hb overlay [56..88)
  //  [88..96)  vp (V proj; attn out; dead after Wo)  -> p1 overlay [88..104)
  //  [96..104) vtb (dead after attn)
  f16* x_hi    = W + 0 * M1;
  f16* wqkv_hi = W + 8 * M1;
  f16* wo_hi   = W + 20 * M1;
  f16* wup_hi  = W + 24 * M1;
  f16* wdn_hi  = W + 40 * M1;
  f16* q_hi    = W + 56 * M1;
  f16* q_lo    = W + 72 * M1;
  f16* vp      = W + 88 * M1;
  f16* vtb     = W + 96 * M1;
  // overlays (checked against live sets per stage):
  f16* x1b   = x_hi;
  float* p0  = (float*)(W + 24 * M1);
  f16* hb    = W + 56 * M1;
  float* p1  = (float*)(W + 88 * M1);
  f16* attno = vp;
  if (ws_size < (size_t)104 * M1 * sizeof(f16)) return;  // 208 MB

  auto cg = [](size_t n4) { size_t g = (n4 + 255) / 256; return (unsigned)(g > 2048 ? 2048 : g); };
  dim3 b256(256);
  dim3 b512(512);
  k_cast<<<cg(2 * M1), b256, 0, stream>>>(x, x_hi, (int)(2 * M1));
  k_cast4<<<dim3(cg(1 * M1), 4), b256, 0, stream>>>(
      Wq, Wk, Wv, Wo,
      wqkv_hi, wqkv_hi + 4 * M1, wqkv_hi + 8 * M1, wo_hi, (int)(1 * M1));
  k_cast2w<<<dim3(cg(4 * M1), 2), b256, 0, stream>>>(
      Wup, Wdn, wup_hi, wdn_hi, (int)(4 * M1));

  // fused Q+K+V projection: 256x256 pipelined, split (hi+lo) OUTPUT for Q,K.
  gemm8<0, 1><<<dim3(24, 16), b512, 0, stream>>>(
      x_hi, wqkv_hi, 2048, 2048, 6144,
      nullptr, nullptr, nullptr, q_hi, q_lo, vp);
  k_transpose_v<<<dim3(32, 2, 32), b256, 0, stream>>>(vp, vtb);
  k_attn<<<dim3(512), b256, 0, stream>>>(
      q_hi, q_lo, q_hi + 8 * M1, q_lo + 8 * M1, vtb, attno);
  // Wo projection + residual -> x1b (f16), legacy 128^2 kernel
  gemm_nt<1, 0, 64><<<dim3(16, 32), b256, 0, stream>>>(
      attno, wo_hi, 2048, 2048, 2048, x, x1b);
  // Up + bias + relu -> hb
  gemm8<2, 0><<<dim3(32, 16), b512, 0, stream>>>(
      x1b, wup_hi, 2048, 2048, 8192,
      bup, nullptr, nullptr, hb, nullptr, nullptr);
  // Down, K split 2x -> f32 partials
  gemm8<3, 0><<<dim3(8, 16, 2), b512, 0, stream>>>(
      hb, wdn_hi, 4096, 8192, 2048,
      nullptr, p0, p1, nullptr, nullptr, nullptr);
  // out = f32(x1b) + p0 + p1
  k_fuseout<<<2048, b256, 0, stream>>>(x1b, p0, p1, out, (int)(2 * M1));
}